// Round 1
// baseline (9279.578 us; speedup 1.0000x reference)
//
#include <hip/hip_runtime.h>
#include <hip/hip_bf16.h>

// ---------------- conv3x3 + bias + relu + maxpool2 (IC=3, OC=64) ----------------
// Thread = one pooled output for 8 consecutive output channels.
// grid: (tilesX*tilesY, OC/8, B), block 256 (16x16 spatial tile)
__global__ void conv_pool_c1(const float* __restrict__ in, float* __restrict__ out,
                             const float* __restrict__ w, const float* __restrict__ bias,
                             int Hin, int Win, int PH, int PW, int tilesX) {
    const int IC = 3, OC = 64;
    int tile = blockIdx.x;
    int ty0 = (tile / tilesX) * 16, tx0 = (tile % tilesX) * 16;
    int t = threadIdx.x;
    int ty = ty0 + (t >> 4), tx = tx0 + (t & 15);
    int b = blockIdx.z;
    int oc0 = blockIdx.y * 8;
    if (ty >= PH || tx >= PW) return;

    int iy = 2 * ty, ix = 2 * tx;
    float acc[8][4];
#pragma unroll
    for (int o = 0; o < 8; ++o)
#pragma unroll
        for (int p = 0; p < 4; ++p) acc[o][p] = 0.f;

#pragma unroll
    for (int ic = 0; ic < IC; ++ic) {
        const float* ip = in + ((size_t)(b * IC + ic) * Hin + iy) * Win + ix;
        float win[4][4];
#pragma unroll
        for (int i = 0; i < 4; ++i)
#pragma unroll
            for (int j = 0; j < 4; ++j) win[i][j] = ip[(size_t)i * Win + j];

#pragma unroll
        for (int o = 0; o < 8; ++o) {
            const float* wp = w + ((size_t)(oc0 + o) * IC + ic) * 9;
            float wr[9];
#pragma unroll
            for (int q = 0; q < 9; ++q) wr[q] = wp[q];
#pragma unroll
            for (int dy = 0; dy < 2; ++dy)
#pragma unroll
                for (int dx = 0; dx < 2; ++dx) {
                    float s = acc[o][dy * 2 + dx];
#pragma unroll
                    for (int ky = 0; ky < 3; ++ky)
#pragma unroll
                        for (int kx = 0; kx < 3; ++kx)
                            s += win[dy + ky][dx + kx] * wr[ky * 3 + kx];
                    acc[o][dy * 2 + dx] = s;
                }
        }
    }
#pragma unroll
    for (int o = 0; o < 8; ++o) {
        float m = fmaxf(fmaxf(acc[o][0], acc[o][1]), fmaxf(acc[o][2], acc[o][3]));
        m = fmaxf(m + bias[oc0 + o], 0.f);
        out[((size_t)(b * OC + oc0 + o) * PH + ty) * PW + tx] = m;
    }
}

// ---------------- conv3x3 + bias + relu + maxpool2 (IC=64, OC=128), LDS-tiled ----
// Block: 16x16 pooled-output tile, 8 output channels. Loop over 64 input channels,
// staging a 34x34 input tile (pitch 36) into LDS each iteration.
__global__ void conv_pool_c2(const float* __restrict__ in, float* __restrict__ out,
                             const float* __restrict__ w, const float* __restrict__ bias,
                             int Hin, int Win, int PH, int PW, int tilesX) {
    const int IC = 64, OC = 128;
    __shared__ float smem[34 * 36];
    int t = threadIdx.x;
    int tile = blockIdx.x;
    int py0 = (tile / tilesX) * 16, px0 = (tile % tilesX) * 16;
    int b = blockIdx.z;
    int oc0 = blockIdx.y * 8;
    int ty = t >> 4, tx = t & 15;
    int py = py0 + ty, px = px0 + tx;
    int iy0 = 2 * py0, ix0 = 2 * px0;

    float acc[8][4];
#pragma unroll
    for (int o = 0; o < 8; ++o)
#pragma unroll
        for (int p = 0; p < 4; ++p) acc[o][p] = 0.f;

    const float* inb = in + (size_t)b * IC * Hin * Win;

    for (int ic = 0; ic < IC; ++ic) {
        const float* ip = inb + (size_t)ic * Hin * Win;
        for (int i = t; i < 34 * 34; i += 256) {
            int r = i / 34, c = i - r * 34;
            int gy = iy0 + r, gx = ix0 + c;
            float v = 0.f;
            if (gy < Hin && gx < Win) v = ip[(size_t)gy * Win + gx];
            smem[r * 36 + c] = v;
        }
        __syncthreads();

        float win[4][4];
        int lr = 2 * ty, lc = 2 * tx;
#pragma unroll
        for (int i = 0; i < 4; ++i) {
            float2 a = *(const float2*)&smem[(lr + i) * 36 + lc];
            float2 bv = *(const float2*)&smem[(lr + i) * 36 + lc + 2];
            win[i][0] = a.x; win[i][1] = a.y; win[i][2] = bv.x; win[i][3] = bv.y;
        }

#pragma unroll
        for (int o = 0; o < 8; ++o) {
            const float* wp = w + ((size_t)(oc0 + o) * IC + ic) * 9;
            float wr[9];
#pragma unroll
            for (int q = 0; q < 9; ++q) wr[q] = wp[q];
#pragma unroll
            for (int dy = 0; dy < 2; ++dy)
#pragma unroll
                for (int dx = 0; dx < 2; ++dx) {
                    float s = acc[o][dy * 2 + dx];
#pragma unroll
                    for (int ky = 0; ky < 3; ++ky)
#pragma unroll
                        for (int kx = 0; kx < 3; ++kx)
                            s += win[dy + ky][dx + kx] * wr[ky * 3 + kx];
                    acc[o][dy * 2 + dx] = s;
                }
        }
        __syncthreads();
    }

    if (py < PH && px < PW) {
#pragma unroll
        for (int o = 0; o < 8; ++o) {
            float m = fmaxf(fmaxf(acc[o][0], acc[o][1]), fmaxf(acc[o][2], acc[o][3]));
            m = fmaxf(m + bias[oc0 + o], 0.f);
            out[((size_t)(b * OC + oc0 + o) * PH + py) * PW + px] = m;
        }
    }
}

// ---------------- depthwise cross-correlation: [62,62] x [14,14] -> [49,49] -----
// Block per (b*128+c). x plane staged in LDS with pitch 63 (conflict-free),
// kernel staged in LDS. Threads compute 4-wide output strips with a sliding
// 17-value register window.
__global__ void xcorr_dw(const float* __restrict__ x, const float* __restrict__ k,
                         float* __restrict__ out) {
    __shared__ float xl[62 * 63 + 20];
    __shared__ float kl[196];
    int bc = blockIdx.x;
    int t = threadIdx.x;

    const float* xp = x + (size_t)bc * 3844;
    for (int i = t; i < 3844; i += 256) {
        int r = i / 62, c = i - r * 62;
        xl[r * 63 + c] = xp[i];
    }
    if (t < 196) kl[t] = k[(size_t)bc * 196 + t];
    __syncthreads();

    for (int s = t; s < 13 * 49; s += 256) {
        int py = s % 49;
        int px0 = (s / 49) * 4;
        float acc0 = 0.f, acc1 = 0.f, acc2 = 0.f, acc3 = 0.f;
        for (int ky = 0; ky < 14; ++ky) {
            const float* row = &xl[(py + ky) * 63 + px0];
            float xr[17];
#pragma unroll
            for (int i = 0; i < 17; ++i) xr[i] = row[i];
            const float* kr = &kl[ky * 14];
#pragma unroll
            for (int kx = 0; kx < 14; ++kx) {
                float kv = kr[kx];
                acc0 += kv * xr[kx];
                acc1 += kv * xr[kx + 1];
                acc2 += kv * xr[kx + 2];
                acc3 += kv * xr[kx + 3];
            }
        }
        float* op = out + (size_t)bc * 2401 + (size_t)py * 49 + px0;
        op[0] = acc0;
        if (px0 + 1 < 49) { op[1] = acc1; op[2] = acc2; op[3] = acc3; }
    }
}

extern "C" void kernel_launch(void* const* d_in, const int* in_sizes, int n_in,
                              void* d_out, int out_size, void* d_ws, size_t ws_size,
                              hipStream_t stream) {
    const float* img = (const float*)d_in[0];
    const float* t1  = (const float*)d_in[1];
    const float* t2  = (const float*)d_in[2];
    const float* w1  = (const float*)d_in[3];
    const float* b1  = (const float*)d_in[4];
    const float* w2  = (const float*)d_in[5];
    const float* b2  = (const float*)d_in[6];
    float* out = (float*)d_out;

    char* ws = (char*)d_ws;
    // bufA: chunked pool1 scratch (8 batches x 64 x 127 x 127) = 33,032,192 B
    // also reused for template pool1 (32 x 64 x 31 x 31 = 7.9 MB)
    float* bufA = (float*)ws;
    float* xf = (float*)(ws + 33032192);        // 32*128*62*62 = 62,980,096 B
    float* k1 = (float*)(ws + 96012288);        // 32*128*14*14 = 3,211,264 B
    float* k2 = (float*)(ws + 99223552);

    // Image path, 4 chunks of 8 batches (keeps pool1 scratch at 33 MB)
    for (int c = 0; c < 4; ++c) {
        const float* imgc = img + (size_t)c * 8 * 3 * 256 * 256;
        float* xfc = xf + (size_t)c * 8 * 128 * 62 * 62;
        // conv1: 256->254 conv ->127 pool; tiles: ceil(127/16)=8 -> 64
        conv_pool_c1<<<dim3(64, 8, 8), 256, 0, stream>>>(imgc, bufA, w1, b1,
                                                         256, 256, 127, 127, 8);
        // conv2: 127->125 conv ->62 pool; tiles: ceil(62/16)=4 -> 16
        conv_pool_c2<<<dim3(16, 16, 8), 256, 0, stream>>>(bufA, xfc, w2, b2,
                                                          127, 127, 62, 62, 4);
    }

    // Template 1 path (all 32 batches; pool1 fits in bufA)
    conv_pool_c1<<<dim3(4, 8, 32), 256, 0, stream>>>(t1, bufA, w1, b1,
                                                     64, 64, 31, 31, 2);
    conv_pool_c2<<<dim3(1, 16, 32), 256, 0, stream>>>(bufA, k1, w2, b2,
                                                      31, 31, 14, 14, 1);
    // Template 2 path
    conv_pool_c1<<<dim3(4, 8, 32), 256, 0, stream>>>(t2, bufA, w1, b1,
                                                     64, 64, 31, 31, 2);
    conv_pool_c2<<<dim3(1, 16, 32), 256, 0, stream>>>(bufA, k2, w2, b2,
                                                      31, 31, 14, 14, 1);

    // Depthwise cross-correlation
    xcorr_dw<<<4096, 256, 0, stream>>>(xf, k1, out);
    xcorr_dw<<<4096, 256, 0, stream>>>(xf, k2, out + (size_t)9834496);
}

// Round 2
// 1969.545 us; speedup vs baseline: 4.7115x; 4.7115x over previous
//
#include <hip/hip_runtime.h>
#include <hip/hip_bf16.h>

// ---------------- conv3x3 + bias + relu + maxpool2 (IC=3, OC=64) ----------------
__global__ void conv_pool_c1(const float* __restrict__ in, float* __restrict__ out,
                             const float* __restrict__ w, const float* __restrict__ bias,
                             int Hin, int Win, int PH, int PW, int tilesX) {
    const int IC = 3, OC = 64;
    int tile = blockIdx.x;
    int ty0 = (tile / tilesX) * 16, tx0 = (tile % tilesX) * 16;
    int t = threadIdx.x;
    int ty = ty0 + (t >> 4), tx = tx0 + (t & 15);
    int b = blockIdx.z;
    int oc0 = blockIdx.y * 8;
    if (ty >= PH || tx >= PW) return;

    int iy = 2 * ty, ix = 2 * tx;
    float acc[8][4];
#pragma unroll
    for (int o = 0; o < 8; ++o)
#pragma unroll
        for (int p = 0; p < 4; ++p) acc[o][p] = 0.f;

#pragma unroll
    for (int ic = 0; ic < IC; ++ic) {
        const float* ip = in + ((size_t)(b * IC + ic) * Hin + iy) * Win + ix;
        float win[4][4];
#pragma unroll
        for (int i = 0; i < 4; ++i)
#pragma unroll
            for (int j = 0; j < 4; ++j) win[i][j] = ip[(size_t)i * Win + j];

#pragma unroll
        for (int o = 0; o < 8; ++o) {
            const float* wp = w + ((size_t)(oc0 + o) * IC + ic) * 9;
            float wr[9];
#pragma unroll
            for (int q = 0; q < 9; ++q) wr[q] = wp[q];
#pragma unroll
            for (int dy = 0; dy < 2; ++dy)
#pragma unroll
                for (int dx = 0; dx < 2; ++dx) {
                    float s = acc[o][dy * 2 + dx];
#pragma unroll
                    for (int ky = 0; ky < 3; ++ky)
#pragma unroll
                        for (int kx = 0; kx < 3; ++kx)
                            s += win[dy + ky][dx + kx] * wr[ky * 3 + kx];
                    acc[o][dy * 2 + dx] = s;
                }
        }
    }
#pragma unroll
    for (int o = 0; o < 8; ++o) {
        float m = fmaxf(fmaxf(acc[o][0], acc[o][1]), fmaxf(acc[o][2], acc[o][3]));
        m = fmaxf(m + bias[oc0 + o], 0.f);
        out[((size_t)(b * OC + oc0 + o) * PH + ty) * PW + tx] = m;
    }
}

// ---------------- conv3x3 + bias + relu + maxpool2 (IC=64, OC=128), LDS-tiled ----
__global__ void conv_pool_c2(const float* __restrict__ in, float* __restrict__ out,
                             const float* __restrict__ w, const float* __restrict__ bias,
                             int Hin, int Win, int PH, int PW, int tilesX) {
    const int IC = 64, OC = 128;
    __shared__ float smem[34 * 36];
    int t = threadIdx.x;
    int tile = blockIdx.x;
    int py0 = (tile / tilesX) * 16, px0 = (tile % tilesX) * 16;
    int b = blockIdx.z;
    int oc0 = blockIdx.y * 8;
    int ty = t >> 4, tx = t & 15;
    int py = py0 + ty, px = px0 + tx;
    int iy0 = 2 * py0, ix0 = 2 * px0;

    float acc[8][4];
#pragma unroll
    for (int o = 0; o < 8; ++o)
#pragma unroll
        for (int p = 0; p < 4; ++p) acc[o][p] = 0.f;

    const float* inb = in + (size_t)b * IC * Hin * Win;

    for (int ic = 0; ic < IC; ++ic) {
        const float* ip = inb + (size_t)ic * Hin * Win;
        for (int i = t; i < 34 * 34; i += 256) {
            int r = i / 34, c = i - r * 34;
            int gy = iy0 + r, gx = ix0 + c;
            float v = 0.f;
            if (gy < Hin && gx < Win) v = ip[(size_t)gy * Win + gx];
            smem[r * 36 + c] = v;
        }
        __syncthreads();

        float win[4][4];
        int lr = 2 * ty, lc = 2 * tx;
#pragma unroll
        for (int i = 0; i < 4; ++i) {
            float2 a = *(const float2*)&smem[(lr + i) * 36 + lc];
            float2 bv = *(const float2*)&smem[(lr + i) * 36 + lc + 2];
            win[i][0] = a.x; win[i][1] = a.y; win[i][2] = bv.x; win[i][3] = bv.y;
        }

#pragma unroll
        for (int o = 0; o < 8; ++o) {
            const float* wp = w + ((size_t)(oc0 + o) * IC + ic) * 9;
            float wr[9];
#pragma unroll
            for (int q = 0; q < 9; ++q) wr[q] = wp[q];
#pragma unroll
            for (int dy = 0; dy < 2; ++dy)
#pragma unroll
                for (int dx = 0; dx < 2; ++dx) {
                    float s = acc[o][dy * 2 + dx];
#pragma unroll
                    for (int ky = 0; ky < 3; ++ky)
#pragma unroll
                        for (int kx = 0; kx < 3; ++kx)
                            s += win[dy + ky][dx + kx] * wr[ky * 3 + kx];
                    acc[o][dy * 2 + dx] = s;
                }
        }
        __syncthreads();
    }

    if (py < PH && px < PW) {
#pragma unroll
        for (int o = 0; o < 8; ++o) {
            float m = fmaxf(fmaxf(acc[o][0], acc[o][1]), fmaxf(acc[o][2], acc[o][3]));
            m = fmaxf(m + bias[oc0 + o], 0.f);
            out[((size_t)(b * OC + oc0 + o) * PH + py) * PW + px] = m;
        }
    }
}

// ---------------- depthwise cross-correlation: [62,62] x [14,14] -> [49,49] -----
// Block per (b*128+c). x plane in LDS (pitch 63, +32 pad for over-read),
// kernel in LDS. Each thread computes an 8-wide output strip using a rolling
// window of NAMED scalar registers (no indexable arrays -> no scratch).
__global__ void xcorr_dw(const float* __restrict__ x, const float* __restrict__ k,
                         float* __restrict__ out) {
    __shared__ float xl[62 * 63 + 32];   // pad: strip over-read up to col 68 on last row
    __shared__ float kl[196];
    int bc = blockIdx.x;
    int t = threadIdx.x;

    const float* xp = x + (size_t)bc * 3844;
    for (int i = t; i < 3844; i += 256) {
        int r = i / 62, c = i - r * 62;
        xl[r * 63 + c] = xp[i];
    }
    if (t < 196) kl[t] = k[(size_t)bc * 196 + t];
    __syncthreads();

    // 7 strips of 8 columns x 49 rows = 343 strips
    for (int s = t; s < 7 * 49; s += 256) {
        int py = s % 49;
        int px0 = (s / 49) * 8;
        float a0 = 0.f, a1 = 0.f, a2 = 0.f, a3 = 0.f;
        float a4 = 0.f, a5 = 0.f, a6 = 0.f, a7 = 0.f;
        for (int ky = 0; ky < 14; ++ky) {
            const float* base = &xl[(py + ky) * 63 + px0];
            const float* kr = &kl[ky * 14];
            float w0 = base[0], w1 = base[1], w2 = base[2], w3 = base[3];
            float w4 = base[4], w5 = base[5], w6 = base[6];
#define XSTEP(KX) do { \
            float kv = kr[KX]; float wn = base[(KX) + 7]; \
            a0 = fmaf(kv, w0, a0); a1 = fmaf(kv, w1, a1); \
            a2 = fmaf(kv, w2, a2); a3 = fmaf(kv, w3, a3); \
            a4 = fmaf(kv, w4, a4); a5 = fmaf(kv, w5, a5); \
            a6 = fmaf(kv, w6, a6); a7 = fmaf(kv, wn, a7); \
            w0 = w1; w1 = w2; w2 = w3; w3 = w4; w4 = w5; w5 = w6; w6 = wn; \
            } while (0)
            XSTEP(0);  XSTEP(1);  XSTEP(2);  XSTEP(3);
            XSTEP(4);  XSTEP(5);  XSTEP(6);  XSTEP(7);
            XSTEP(8);  XSTEP(9);  XSTEP(10); XSTEP(11);
            XSTEP(12); XSTEP(13);
#undef XSTEP
        }
        float* op = out + (size_t)bc * 2401 + (size_t)py * 49 + px0;
        op[0] = a0;
        if (px0 < 48) {   // px0 <= 40: full 8-wide strip valid (px0+7 <= 47)
            op[1] = a1; op[2] = a2; op[3] = a3;
            op[4] = a4; op[5] = a5; op[6] = a6; op[7] = a7;
        }
    }
}

extern "C" void kernel_launch(void* const* d_in, const int* in_sizes, int n_in,
                              void* d_out, int out_size, void* d_ws, size_t ws_size,
                              hipStream_t stream) {
    const float* img = (const float*)d_in[0];
    const float* t1  = (const float*)d_in[1];
    const float* t2  = (const float*)d_in[2];
    const float* w1  = (const float*)d_in[3];
    const float* b1  = (const float*)d_in[4];
    const float* w2  = (const float*)d_in[5];
    const float* b2  = (const float*)d_in[6];
    float* out = (float*)d_out;

    char* ws = (char*)d_ws;
    // bufA: chunked pool1 scratch (8 batches x 64 x 127 x 127) = 33,032,192 B
    float* bufA = (float*)ws;
    float* xf = (float*)(ws + 33032192);        // 32*128*62*62 = 62,980,096 B
    float* k1 = (float*)(ws + 96012288);        // 32*128*14*14 = 3,211,264 B
    float* k2 = (float*)(ws + 99223552);

    // Image path, 4 chunks of 8 batches
    for (int c = 0; c < 4; ++c) {
        const float* imgc = img + (size_t)c * 8 * 3 * 256 * 256;
        float* xfc = xf + (size_t)c * 8 * 128 * 62 * 62;
        conv_pool_c1<<<dim3(64, 8, 8), 256, 0, stream>>>(imgc, bufA, w1, b1,
                                                         256, 256, 127, 127, 8);
        conv_pool_c2<<<dim3(16, 16, 8), 256, 0, stream>>>(bufA, xfc, w2, b2,
                                                          127, 127, 62, 62, 4);
    }

    // Template paths
    conv_pool_c1<<<dim3(4, 8, 32), 256, 0, stream>>>(t1, bufA, w1, b1,
                                                     64, 64, 31, 31, 2);
    conv_pool_c2<<<dim3(1, 16, 32), 256, 0, stream>>>(bufA, k1, w2, b2,
                                                      31, 31, 14, 14, 1);
    conv_pool_c1<<<dim3(4, 8, 32), 256, 0, stream>>>(t2, bufA, w1, b1,
                                                     64, 64, 31, 31, 2);
    conv_pool_c2<<<dim3(1, 16, 32), 256, 0, stream>>>(bufA, k2, w2, b2,
                                                      31, 31, 14, 14, 1);

    // Depthwise cross-correlation
    xcorr_dw<<<4096, 256, 0, stream>>>(xf, k1, out);
    xcorr_dw<<<4096, 256, 0, stream>>>(xf, k2, out + (size_t)9834496);
}

// Round 3
// 655.208 us; speedup vs baseline: 14.1628x; 3.0060x over previous
//
#include <hip/hip_runtime.h>
#include <hip/hip_bf16.h>

typedef __attribute__((ext_vector_type(8))) short bf16x8;
typedef __attribute__((ext_vector_type(4))) float f32x4;

// ---------------- conv3x3 + bias + relu + maxpool2 (IC=3, OC=64), NHWC bf16 out --
// Thread = one pooled output pixel for 8 consecutive output channels.
__global__ void conv_pool_c1_nhwc(const float* __restrict__ in, __hip_bfloat16* __restrict__ out,
                                  const float* __restrict__ w, const float* __restrict__ bias,
                                  int Hin, int Win, int PH, int PW, int tilesX) {
    const int IC = 3, OC = 64;
    int tile = blockIdx.x;
    int ty0 = (tile / tilesX) * 16, tx0 = (tile % tilesX) * 16;
    int t = threadIdx.x;
    int ty = ty0 + (t >> 4), tx = tx0 + (t & 15);
    int b = blockIdx.z;
    int oc0 = blockIdx.y * 8;
    if (ty >= PH || tx >= PW) return;

    int iy = 2 * ty, ix = 2 * tx;
    float acc[8][4];
#pragma unroll
    for (int o = 0; o < 8; ++o)
#pragma unroll
        for (int p = 0; p < 4; ++p) acc[o][p] = 0.f;

#pragma unroll
    for (int ic = 0; ic < IC; ++ic) {
        const float* ip = in + ((size_t)(b * IC + ic) * Hin + iy) * Win + ix;
        float win[4][4];
#pragma unroll
        for (int i = 0; i < 4; ++i)
#pragma unroll
            for (int j = 0; j < 4; ++j) win[i][j] = ip[(size_t)i * Win + j];

#pragma unroll
        for (int o = 0; o < 8; ++o) {
            const float* wp = w + ((size_t)(oc0 + o) * IC + ic) * 9;
            float wr[9];
#pragma unroll
            for (int q = 0; q < 9; ++q) wr[q] = wp[q];
#pragma unroll
            for (int dy = 0; dy < 2; ++dy)
#pragma unroll
                for (int dx = 0; dx < 2; ++dx) {
                    float s = acc[o][dy * 2 + dx];
#pragma unroll
                    for (int ky = 0; ky < 3; ++ky)
#pragma unroll
                        for (int kx = 0; kx < 3; ++kx)
                            s += win[dy + ky][dx + kx] * wr[ky * 3 + kx];
                    acc[o][dy * 2 + dx] = s;
                }
        }
    }
    union { __hip_bfloat16 h[8]; uint4 v; } pk;
#pragma unroll
    for (int o = 0; o < 8; ++o) {
        float m = fmaxf(fmaxf(acc[o][0], acc[o][1]), fmaxf(acc[o][2], acc[o][3]));
        m = fmaxf(m + bias[oc0 + o], 0.f);
        pk.h[o] = __float2bfloat16(m);
    }
    // NHWC: [b][ty][tx][64]
    *(uint4*)&out[(((size_t)b * PH + ty) * PW + tx) * 64 + oc0] = pk.v;
}

// ---------------- weight transform: [128][64][3][3] f32 -> [128][(ky*3+kx)*64+ic] bf16
__global__ void wt_xform(const float* __restrict__ w, __hip_bfloat16* __restrict__ wt) {
    int i = blockIdx.x * 256 + threadIdx.x;
    if (i >= 128 * 576) return;
    int oc = i / 576, k = i - oc * 576;
    int kk = k >> 6, ic = k & 63;     // kk = ky*3+kx
    int ky = kk / 3, kx = kk - ky * 3;
    wt[i] = __float2bfloat16(w[(((size_t)oc * 64 + ic) * 3 + ky) * 3 + kx]);
}

// ---------------- conv2 implicit-GEMM on MFMA + fused bias/relu/maxpool ----------
// Input: NHWC bf16 [B][H1][W1][64]. Weights: [128][576] bf16 (k=(ky*3+kx)*64+ic).
// Output: NCHW f32 [B][128][PH][PW] (pooled).
// Block: 256 thr = 4 waves (2 oc-halves x 2 pixel-halves); tile = 128 oc x (16x8) conv px.
__global__ void conv2_mfma(const __hip_bfloat16* __restrict__ xin,
                           const __hip_bfloat16* __restrict__ wt,
                           const float* __restrict__ bias, float* __restrict__ out,
                           int H1, int W1, int PH, int PW, int tilesX) {
    __shared__ uint4 xl4[10 * 18 * 8];   // 10 rows x 18 cols x 8 slots(8 bf16) = 23040 B

    int t = threadIdx.x;
    int tile = blockIdx.x;
    int tileY = tile / tilesX, tileX = tile - tileY * tilesX;
    int b = blockIdx.z;
    int y0 = tileY * 8, x0 = tileX * 16;   // conv-pixel origin

    // ---- stage input tile (zero-fill OOB), swizzled: slot si -> si ^ (col&7)
    const __hip_bfloat16* xb = xin + (size_t)b * H1 * W1 * 64;
    for (int s = t; s < 1440; s += 256) {
        int pixel = s >> 3, si = s & 7;
        int row = pixel / 18, col = pixel - row * 18;
        int gy = y0 + row, gx = x0 + col;
        uint4 v = make_uint4(0, 0, 0, 0);
        if (gy < H1 && gx < W1)
            v = *(const uint4*)&xb[((size_t)gy * W1 + gx) * 64 + si * 8];
        xl4[(pixel << 3) | (si ^ (col & 7))] = v;
    }
    __syncthreads();

    int lane = t & 63;
    int wid = t >> 6;
    int wr = wid >> 1;       // oc half (0/1)
    int wc = wid & 1;        // pixel half (0/1): rows wc*4..wc*4+3 of the 16x8 tile
    int l15 = lane & 15, l4 = lane >> 4;

    f32x4 acc[4][4];
#pragma unroll
    for (int m = 0; m < 4; ++m)
#pragma unroll
        for (int n = 0; n < 4; ++n) acc[m][n] = (f32x4)(0.f);

    const __hip_bfloat16* abase = wt + ((size_t)(wr * 64 + l15)) * 576 + l4 * 8;

#pragma unroll
    for (int kk = 0; kk < 9; ++kk) {
        const int ky = kk / 3, kx = kk - ky * 3;
        const int col = l15 + kx;
        const int csw = col & 7;
#pragma unroll
        for (int h = 0; h < 2; ++h) {
            const int k0 = kk * 64 + h * 32;
            bf16x8 af[4], bfv[4];
#pragma unroll
            for (int m = 0; m < 4; ++m)
                af[m] = *(const bf16x8*)(abase + m * 16 * 576 + k0);
            const int sidx = (h * 4 + l4) ^ csw;
#pragma unroll
            for (int n = 0; n < 4; ++n) {
                int row = wc * 4 + n + ky;
                bfv[n] = *(const bf16x8*)&xl4[((row * 18 + col) << 3) | sidx];
            }
#pragma unroll
            for (int m = 0; m < 4; ++m)
#pragma unroll
                for (int n = 0; n < 4; ++n)
                    acc[m][n] = __builtin_amdgcn_mfma_f32_16x16x32_bf16(
                        af[m], bfv[n], acc[m][n], 0, 0, 0);
        }
    }

    // ---- epilogue: maxpool 2x2 (n-pairs vertical, lane-pairs horizontal) + bias + relu
    int qx = tileX * 8 + (l15 >> 1);
    bool xok = ((lane & 1) == 0) && (qx < PW);
#pragma unroll
    for (int m = 0; m < 4; ++m) {
        int ocb = wr * 64 + m * 16 + l4 * 4;
#pragma unroll
        for (int np = 0; np < 2; ++np) {
            int qy = tileY * 4 + wc * 2 + np;
#pragma unroll
            for (int r = 0; r < 4; ++r) {
                float v = fmaxf(acc[m][2 * np][r], acc[m][2 * np + 1][r]);
                v = fmaxf(v, __shfl_xor(v, 1));
                if (xok && qy < PH) {
                    float u = fmaxf(v + bias[ocb + r], 0.f);
                    out[(((size_t)b * 128 + ocb + r) * PH + qy) * PW + qx] = u;
                }
            }
        }
    }
}

// ---------------- depthwise cross-correlation: [62,62] x [14,14] -> [49,49] -----
__global__ void xcorr_dw(const float* __restrict__ x, const float* __restrict__ k,
                         float* __restrict__ out) {
    __shared__ float xl[62 * 63 + 32];
    __shared__ float kl[196];
    int bc = blockIdx.x;
    int t = threadIdx.x;

    const float* xp = x + (size_t)bc * 3844;
    for (int i = t; i < 3844; i += 256) {
        int r = i / 62, c = i - r * 62;
        xl[r * 63 + c] = xp[i];
    }
    if (t < 196) kl[t] = k[(size_t)bc * 196 + t];
    __syncthreads();

    for (int s = t; s < 7 * 49; s += 256) {
        int py = s % 49;
        int px0 = (s / 49) * 8;
        float a0 = 0.f, a1 = 0.f, a2 = 0.f, a3 = 0.f;
        float a4 = 0.f, a5 = 0.f, a6 = 0.f, a7 = 0.f;
        for (int ky = 0; ky < 14; ++ky) {
            const float* base = &xl[(py + ky) * 63 + px0];
            const float* kr = &kl[ky * 14];
            float w0 = base[0], w1 = base[1], w2 = base[2], w3 = base[3];
            float w4 = base[4], w5 = base[5], w6 = base[6];
#define XSTEP(KX) do { \
            float kv = kr[KX]; float wn = base[(KX) + 7]; \
            a0 = fmaf(kv, w0, a0); a1 = fmaf(kv, w1, a1); \
            a2 = fmaf(kv, w2, a2); a3 = fmaf(kv, w3, a3); \
            a4 = fmaf(kv, w4, a4); a5 = fmaf(kv, w5, a5); \
            a6 = fmaf(kv, w6, a6); a7 = fmaf(kv, wn, a7); \
            w0 = w1; w1 = w2; w2 = w3; w3 = w4; w4 = w5; w5 = w6; w6 = wn; \
            } while (0)
            XSTEP(0);  XSTEP(1);  XSTEP(2);  XSTEP(3);
            XSTEP(4);  XSTEP(5);  XSTEP(6);  XSTEP(7);
            XSTEP(8);  XSTEP(9);  XSTEP(10); XSTEP(11);
            XSTEP(12); XSTEP(13);
#undef XSTEP
        }
        float* op = out + (size_t)bc * 2401 + (size_t)py * 49 + px0;
        op[0] = a0;
        if (px0 < 48) {
            op[1] = a1; op[2] = a2; op[3] = a3;
            op[4] = a4; op[5] = a5; op[6] = a6; op[7] = a7;
        }
    }
}

extern "C" void kernel_launch(void* const* d_in, const int* in_sizes, int n_in,
                              void* d_out, int out_size, void* d_ws, size_t ws_size,
                              hipStream_t stream) {
    const float* img = (const float*)d_in[0];
    const float* t1  = (const float*)d_in[1];
    const float* t2  = (const float*)d_in[2];
    const float* w1  = (const float*)d_in[3];
    const float* b1  = (const float*)d_in[4];
    const float* w2  = (const float*)d_in[5];
    const float* b2  = (const float*)d_in[6];
    float* out = (float*)d_out;

    char* ws = (char*)d_ws;
    // bufA: conv1 NHWC bf16 scratch. image chunk: 8*127*127*64*2 = 16,516,096 B
    __hip_bfloat16* bufA = (__hip_bfloat16*)ws;
    __hip_bfloat16* w2t  = (__hip_bfloat16*)(ws + 16516096);   // 128*576*2 = 147,456
    float* xf = (float*)(ws + 16663552);                        // 32*128*62*62*4 = 62,980,096
    float* k1 = (float*)(ws + 79643648);                        // 32*128*14*14*4 = 3,211,264
    float* k2 = (float*)(ws + 82854912);

    wt_xform<<<288, 256, 0, stream>>>(w2, w2t);

    // Image path, 4 chunks of 8 batches
    for (int c = 0; c < 4; ++c) {
        const float* imgc = img + (size_t)c * 8 * 3 * 256 * 256;
        float* xfc = xf + (size_t)c * 8 * 128 * 62 * 62;
        conv_pool_c1_nhwc<<<dim3(64, 8, 8), 256, 0, stream>>>(imgc, bufA, w1, b1,
                                                              256, 256, 127, 127, 8);
        // conv pixels used: 124x124 -> tiles 8x16
        conv2_mfma<<<dim3(128, 1, 8), 256, 0, stream>>>(bufA, w2t, b2, xfc,
                                                        127, 127, 62, 62, 8);
    }

    // Template paths (conv pixels used: 28x28 -> tiles 2x4)
    conv_pool_c1_nhwc<<<dim3(4, 8, 32), 256, 0, stream>>>(t1, bufA, w1, b1,
                                                          64, 64, 31, 31, 2);
    conv2_mfma<<<dim3(8, 1, 32), 256, 0, stream>>>(bufA, w2t, b2, k1,
                                                   31, 31, 14, 14, 2);
    conv_pool_c1_nhwc<<<dim3(4, 8, 32), 256, 0, stream>>>(t2, bufA, w1, b1,
                                                          64, 64, 31, 31, 2);
    conv2_mfma<<<dim3(8, 1, 32), 256, 0, stream>>>(bufA, w2t, b2, k2,
                                                   31, 31, 14, 14, 2);

    // Depthwise cross-correlation
    xcorr_dw<<<4096, 256, 0, stream>>>(xf, k1, out);
    xcorr_dw<<<4096, 256, 0, stream>>>(xf, k2, out + (size_t)9834496);
}

// Round 4
// 618.452 us; speedup vs baseline: 15.0045x; 1.0594x over previous
//
#include <hip/hip_runtime.h>
#include <hip/hip_bf16.h>
#include <hip/hip_fp16.h>

typedef __attribute__((ext_vector_type(8))) short bf16x8;
typedef __attribute__((ext_vector_type(4))) float f32x4;
typedef __attribute__((ext_vector_type(2))) _Float16 f16x2;

__device__ __forceinline__ float dot2f16(unsigned a, unsigned b, float c) {
#if __has_builtin(__builtin_amdgcn_fdot2)
    return __builtin_amdgcn_fdot2(__builtin_bit_cast(f16x2, a),
                                  __builtin_bit_cast(f16x2, b), c, false);
#else
    union { unsigned u; __half2 h; } ua, ub;
    ua.u = a; ub.u = b;
    return c + __low2float(ua.h) * __low2float(ub.h)
             + __high2float(ua.h) * __high2float(ub.h);
#endif
}

// ---------------- conv3x3 + bias + relu + maxpool2 (IC=3, OC=64), NHWC bf16 out --
__global__ void conv_pool_c1_nhwc(const float* __restrict__ in, __hip_bfloat16* __restrict__ out,
                                  const float* __restrict__ w, const float* __restrict__ bias,
                                  int Hin, int Win, int PH, int PW, int tilesX) {
    const int IC = 3, OC = 64;
    int tile = blockIdx.x;
    int ty0 = (tile / tilesX) * 16, tx0 = (tile % tilesX) * 16;
    int t = threadIdx.x;
    int ty = ty0 + (t >> 4), tx = tx0 + (t & 15);
    int b = blockIdx.z;
    int oc0 = blockIdx.y * 8;
    if (ty >= PH || tx >= PW) return;

    int iy = 2 * ty, ix = 2 * tx;
    float acc[8][4];
#pragma unroll
    for (int o = 0; o < 8; ++o)
#pragma unroll
        for (int p = 0; p < 4; ++p) acc[o][p] = 0.f;

#pragma unroll
    for (int ic = 0; ic < IC; ++ic) {
        const float* ip = in + ((size_t)(b * IC + ic) * Hin + iy) * Win + ix;
        float win[4][4];
#pragma unroll
        for (int i = 0; i < 4; ++i)
#pragma unroll
            for (int j = 0; j < 4; ++j) win[i][j] = ip[(size_t)i * Win + j];

#pragma unroll
        for (int o = 0; o < 8; ++o) {
            const float* wp = w + ((size_t)(oc0 + o) * IC + ic) * 9;
            float wr[9];
#pragma unroll
            for (int q = 0; q < 9; ++q) wr[q] = wp[q];
#pragma unroll
            for (int dy = 0; dy < 2; ++dy)
#pragma unroll
                for (int dx = 0; dx < 2; ++dx) {
                    float s = acc[o][dy * 2 + dx];
#pragma unroll
                    for (int ky = 0; ky < 3; ++ky)
#pragma unroll
                        for (int kx = 0; kx < 3; ++kx)
                            s += win[dy + ky][dx + kx] * wr[ky * 3 + kx];
                    acc[o][dy * 2 + dx] = s;
                }
        }
    }
    union { __hip_bfloat16 h[8]; uint4 v; } pk;
#pragma unroll
    for (int o = 0; o < 8; ++o) {
        float m = fmaxf(fmaxf(acc[o][0], acc[o][1]), fmaxf(acc[o][2], acc[o][3]));
        m = fmaxf(m + bias[oc0 + o], 0.f);
        pk.h[o] = __float2bfloat16(m);
    }
    *(uint4*)&out[(((size_t)b * PH + ty) * PW + tx) * 64 + oc0] = pk.v;
}

// ---------------- weight transform: [128][64][3][3] f32 -> [128][(ky*3+kx)*64+ic] bf16
__global__ void wt_xform(const float* __restrict__ w, __hip_bfloat16* __restrict__ wt) {
    int i = blockIdx.x * 256 + threadIdx.x;
    if (i >= 128 * 576) return;
    int oc = i / 576, k = i - oc * 576;
    int kk = k >> 6, ic = k & 63;
    int ky = kk / 3, kx = kk - ky * 3;
    wt[i] = __float2bfloat16(w[(((size_t)oc * 64 + ic) * 3 + ky) * 3 + kx]);
}

// ---------------- conv2 implicit-GEMM on MFMA + fused bias/relu/maxpool, f16 NCHW out
__global__ void conv2_mfma(const __hip_bfloat16* __restrict__ xin,
                           const __hip_bfloat16* __restrict__ wt,
                           const float* __restrict__ bias, __half* __restrict__ out,
                           int H1, int W1, int PH, int PW, int tilesX) {
    __shared__ uint4 xl4[10 * 18 * 8];   // 23040 B; reused as 8KB pooled-store buffer

    int t = threadIdx.x;
    int tile = blockIdx.x;
    int tileY = tile / tilesX, tileX = tile - tileY * tilesX;
    int b = blockIdx.z;
    int y0 = tileY * 8, x0 = tileX * 16;

    const __hip_bfloat16* xb = xin + (size_t)b * H1 * W1 * 64;
    for (int s = t; s < 1440; s += 256) {
        int pixel = s >> 3, si = s & 7;
        int row = pixel / 18, col = pixel - row * 18;
        int gy = y0 + row, gx = x0 + col;
        uint4 v = make_uint4(0, 0, 0, 0);
        if (gy < H1 && gx < W1)
            v = *(const uint4*)&xb[((size_t)gy * W1 + gx) * 64 + si * 8];
        xl4[(pixel << 3) | (si ^ (col & 7))] = v;
    }
    __syncthreads();

    int lane = t & 63;
    int wid = t >> 6;
    int wr = wid >> 1;
    int wc = wid & 1;
    int l15 = lane & 15, l4 = lane >> 4;

    f32x4 acc[4][4];
#pragma unroll
    for (int m = 0; m < 4; ++m)
#pragma unroll
        for (int n = 0; n < 4; ++n) acc[m][n] = (f32x4)(0.f);

    const __hip_bfloat16* abase = wt + ((size_t)(wr * 64 + l15)) * 576 + l4 * 8;

#pragma unroll
    for (int kk = 0; kk < 9; ++kk) {
        const int ky = kk / 3, kx = kk - ky * 3;
        const int col = l15 + kx;
        const int csw = col & 7;
#pragma unroll
        for (int h = 0; h < 2; ++h) {
            const int k0 = kk * 64 + h * 32;
            bf16x8 af[4], bfv[4];
#pragma unroll
            for (int m = 0; m < 4; ++m)
                af[m] = *(const bf16x8*)(abase + m * 16 * 576 + k0);
            const int sidx = (h * 4 + l4) ^ csw;
#pragma unroll
            for (int n = 0; n < 4; ++n) {
                int row = wc * 4 + n + ky;
                bfv[n] = *(const bf16x8*)&xl4[((row * 18 + col) << 3) | sidx];
            }
#pragma unroll
            for (int m = 0; m < 4; ++m)
#pragma unroll
                for (int n = 0; n < 4; ++n)
                    acc[m][n] = __builtin_amdgcn_mfma_f32_16x16x32_bf16(
                        af[m], bfv[n], acc[m][n], 0, 0, 0);
        }
    }

    // ---- epilogue: pool + bias + relu into LDS [128 oc][4 qy][8 qx] f16, then
    //      cooperative contiguous NCHW stores
    __syncthreads();
    __half* plds = (__half*)xl4;
#pragma unroll
    for (int m = 0; m < 4; ++m) {
        int ocb = wr * 64 + m * 16 + l4 * 4;
#pragma unroll
        for (int np = 0; np < 2; ++np) {
            int qyl = wc * 2 + np;
#pragma unroll
            for (int r = 0; r < 4; ++r) {
                float v = fmaxf(acc[m][2 * np][r], acc[m][2 * np + 1][r]);
                v = fmaxf(v, __shfl_xor(v, 1));
                if ((lane & 1) == 0) {
                    float u = fmaxf(v + bias[ocb + r], 0.f);
                    plds[((ocb + r) * 4 + qyl) * 8 + (l15 >> 1)] = __float2half(u);
                }
            }
        }
    }
    __syncthreads();

    int qx0 = tileX * 8, qy0 = tileY * 4;
    for (int i = t; i < 512; i += 256) {
        int oc = i >> 2, qy = i & 3;
        int gqy = qy0 + qy;
        if (gqy < PH) {
            __half* dst = out + (((size_t)b * 128 + oc) * PH + gqy) * PW + qx0;
            const __half* src = &plds[i * 8];
            if (qx0 + 8 <= PW) {
                *(uint4*)dst = *(const uint4*)src;
            } else {
                for (int q = 0; q < 8 && qx0 + q < PW; ++q) dst[q] = src[q];
            }
        }
    }
}

// ---------------- fused dual depthwise xcorr, packed f16 dot2 --------------------
// Block 384 thr per (b,c): stage x plane [62][66 pitch] f16 + both kernels as
// f16 pairs; each thread computes one 8-wide strip for BOTH outputs.
__global__ void xcorr_dual(const __half* __restrict__ x, const __half* __restrict__ k1,
                           const __half* __restrict__ k2,
                           float* __restrict__ out1, float* __restrict__ out2) {
    __shared__ __half xl[62 * 66 + 8];
    __shared__ unsigned kl[224];           // [0..111]=k1 pairs, [112..223]=k2; pitch 8/ky
    int bc = blockIdx.x;
    int t = threadIdx.x;

    const unsigned* xp = (const unsigned*)(x + (size_t)bc * 3844);   // 1922 dwords
    unsigned* xld = (unsigned*)xl;
    for (int d = t; d < 1922; d += 384) {
        int r = d / 31, c2 = d - r * 31;
        xld[r * 33 + c2] = xp[d];
    }
    if (t < 98) {
        int ky = t / 7, p = t - ky * 7;
        kl[ky * 8 + p] = ((const unsigned*)(k1 + (size_t)bc * 196))[t];
    } else if (t < 196) {
        int i = t - 98;
        int ky = i / 7, p = i - ky * 7;
        kl[112 + ky * 8 + p] = ((const unsigned*)(k2 + (size_t)bc * 196))[i];
    }
    __syncthreads();

    if (t >= 343) return;
    int py = t % 49;
    int px0 = (t / 49) * 8;

    float a10 = 0.f, a11 = 0.f, a12 = 0.f, a13 = 0.f;
    float a14 = 0.f, a15 = 0.f, a16 = 0.f, a17 = 0.f;
    float a20 = 0.f, a21 = 0.f, a22 = 0.f, a23 = 0.f;
    float a24 = 0.f, a25 = 0.f, a26 = 0.f, a27 = 0.f;

    for (int ky = 0; ky < 14; ++ky) {
        const unsigned* row = (const unsigned*)&xl[(py + ky) * 66 + px0];
        unsigned e0 = row[0], e1 = row[1], e2 = row[2], e3 = row[3], e4 = row[4];
        unsigned e5 = row[5], e6 = row[6], e7 = row[7], e8 = row[8], e9 = row[9];
        unsigned e10 = row[10];
        unsigned o0 = (e0 >> 16) | (e1 << 16);
        unsigned o1 = (e1 >> 16) | (e2 << 16);
        unsigned o2 = (e2 >> 16) | (e3 << 16);
        unsigned o3 = (e3 >> 16) | (e4 << 16);
        unsigned o4 = (e4 >> 16) | (e5 << 16);
        unsigned o5 = (e5 >> 16) | (e6 << 16);
        unsigned o6 = (e6 >> 16) | (e7 << 16);
        unsigned o7 = (e7 >> 16) | (e8 << 16);
        unsigned o8 = (e8 >> 16) | (e9 << 16);
        unsigned o9 = (e9 >> 16) | (e10 << 16);
        int kb = ky * 8;
#define PSTEP(P, EA, OA, EB, OB, EC, OC, ED, OD) do { \
        unsigned kp1 = kl[kb + (P)]; unsigned kp2 = kl[kb + 112 + (P)]; \
        a10 = dot2f16(kp1, EA, a10); a20 = dot2f16(kp2, EA, a20); \
        a11 = dot2f16(kp1, OA, a11); a21 = dot2f16(kp2, OA, a21); \
        a12 = dot2f16(kp1, EB, a12); a22 = dot2f16(kp2, EB, a22); \
        a13 = dot2f16(kp1, OB, a13); a23 = dot2f16(kp2, OB, a23); \
        a14 = dot2f16(kp1, EC, a14); a24 = dot2f16(kp2, EC, a24); \
        a15 = dot2f16(kp1, OC, a15); a25 = dot2f16(kp2, OC, a25); \
        a16 = dot2f16(kp1, ED, a16); a26 = dot2f16(kp2, ED, a26); \
        a17 = dot2f16(kp1, OD, a17); a27 = dot2f16(kp2, OD, a27); \
        } while (0)
        PSTEP(0, e0, o0, e1, o1, e2, o2, e3, o3);
        PSTEP(1, e1, o1, e2, o2, e3, o3, e4, o4);
        PSTEP(2, e2, o2, e3, o3, e4, o4, e5, o5);
        PSTEP(3, e3, o3, e4, o4, e5, o5, e6, o6);
        PSTEP(4, e4, o4, e5, o5, e6, o6, e7, o7);
        PSTEP(5, e5, o5, e6, o6, e7, o7, e8, o8);
        PSTEP(6, e6, o6, e7, o7, e8, o8, e9, o9);
#undef PSTEP
    }

    size_t ob = (size_t)bc * 2401 + (size_t)py * 49 + px0;
    out1[ob] = a10; out2[ob] = a20;
    if (px0 < 48) {
        out1[ob + 1] = a11; out1[ob + 2] = a12; out1[ob + 3] = a13;
        out1[ob + 4] = a14; out1[ob + 5] = a15; out1[ob + 6] = a16; out1[ob + 7] = a17;
        out2[ob + 1] = a21; out2[ob + 2] = a22; out2[ob + 3] = a23;
        out2[ob + 4] = a24; out2[ob + 5] = a25; out2[ob + 6] = a26; out2[ob + 7] = a27;
    }
}

extern "C" void kernel_launch(void* const* d_in, const int* in_sizes, int n_in,
                              void* d_out, int out_size, void* d_ws, size_t ws_size,
                              hipStream_t stream) {
    const float* img = (const float*)d_in[0];
    const float* t1  = (const float*)d_in[1];
    const float* t2  = (const float*)d_in[2];
    const float* w1  = (const float*)d_in[3];
    const float* b1  = (const float*)d_in[4];
    const float* w2  = (const float*)d_in[5];
    const float* b2  = (const float*)d_in[6];
    float* out = (float*)d_out;

    char* ws = (char*)d_ws;
    __hip_bfloat16* bufA = (__hip_bfloat16*)ws;                 // 16,516,096 B
    __hip_bfloat16* w2t  = (__hip_bfloat16*)(ws + 16516096);    // 147,456 B
    __half* xf = (__half*)(ws + 16663552);                      // 32*128*62*62*2 = 31,490,048
    __half* k1 = (__half*)(ws + 48153600);                      // 32*128*196*2 = 1,605,632
    __half* k2 = (__half*)(ws + 49759232);

    wt_xform<<<288, 256, 0, stream>>>(w2, w2t);

    for (int c = 0; c < 4; ++c) {
        const float* imgc = img + (size_t)c * 8 * 3 * 256 * 256;
        __half* xfc = xf + (size_t)c * 8 * 128 * 62 * 62;
        conv_pool_c1_nhwc<<<dim3(64, 8, 8), 256, 0, stream>>>(imgc, bufA, w1, b1,
                                                              256, 256, 127, 127, 8);
        conv2_mfma<<<dim3(128, 1, 8), 256, 0, stream>>>(bufA, w2t, b2, xfc,
                                                        127, 127, 62, 62, 8);
    }

    conv_pool_c1_nhwc<<<dim3(4, 8, 32), 256, 0, stream>>>(t1, bufA, w1, b1,
                                                          64, 64, 31, 31, 2);
    conv2_mfma<<<dim3(8, 1, 32), 256, 0, stream>>>(bufA, w2t, b2, k1,
                                                   31, 31, 14, 14, 2);
    conv_pool_c1_nhwc<<<dim3(4, 8, 32), 256, 0, stream>>>(t2, bufA, w1, b1,
                                                          64, 64, 31, 31, 2);
    conv2_mfma<<<dim3(8, 1, 32), 256, 0, stream>>>(bufA, w2t, b2, k2,
                                                   31, 31, 14, 14, 2);

    xcorr_dual<<<4096, 384, 0, stream>>>(xf, k1, k2, out, out + (size_t)9834496);
}

// Round 5
// 497.831 us; speedup vs baseline: 18.6400x; 1.2423x over previous
//
#include <hip/hip_runtime.h>
#include <hip/hip_bf16.h>
#include <hip/hip_fp16.h>

typedef __attribute__((ext_vector_type(8))) short bf16x8;
typedef __attribute__((ext_vector_type(4))) float f32x4;
typedef __attribute__((ext_vector_type(2))) _Float16 f16x2;

__device__ __forceinline__ float dot2f16(unsigned a, unsigned b, float c) {
#if __has_builtin(__builtin_amdgcn_fdot2)
    return __builtin_amdgcn_fdot2(__builtin_bit_cast(f16x2, a),
                                  __builtin_bit_cast(f16x2, b), c, false);
#else
    union { unsigned u; __half2 h; } ua, ub;
    ua.u = a; ub.u = b;
    return c + __low2float(ua.h) * __low2float(ub.h)
             + __high2float(ua.h) * __high2float(ub.h);
#endif
}

// ---------------- weight transforms -------------------------------------------
// w1 [64][3][3][3] f32 -> w1t [64][32] bf16 (k = ic*9+ky*3+kx, pad 27..31 = 0)
// w2 [128][64][3][3] f32 -> w2t [128][(ky*3+kx)*64+ic] bf16
__global__ void wt_xform_all(const float* __restrict__ w1, const float* __restrict__ w2,
                             __hip_bfloat16* __restrict__ w1t, __hip_bfloat16* __restrict__ w2t) {
    int i = blockIdx.x * 256 + threadIdx.x;
    if (i < 2048) {
        int oc = i >> 5, k = i & 31;
        w1t[i] = (k < 27) ? __float2bfloat16(w1[oc * 27 + k]) : __float2bfloat16(0.f);
        return;
    }
    int j = i - 2048;
    if (j < 128 * 576) {
        int oc = j / 576, k = j - oc * 576;
        int kk = k >> 6, ic = k & 63;
        int ky = kk / 3, kx = kk - ky * 3;
        w2t[j] = __float2bfloat16(w2[(((size_t)oc * 64 + ic) * 3 + ky) * 3 + kx]);
    }
}

// ---------------- conv1 implicit-GEMM on MFMA + fused bias/relu/maxpool ---------
// Input NCHW f32 [B][3][H][W]; weights w1t [64][32] bf16; output NHWC bf16.
// Block 256 = 4 waves; tile = 16x16 conv px (wave w: rows w*4..w*4+3), 64 oc.
__global__ void conv1_mfma(const float* __restrict__ in,
                           const __hip_bfloat16* __restrict__ w1t,
                           const float* __restrict__ bias,
                           __hip_bfloat16* __restrict__ out,
                           int Hin, int Win, int PH, int PW, int tilesX) {
    __shared__ unsigned short xs[3 * 324];   // [ic][18 rows][18 cols] bf16 bits
    int t = threadIdx.x;
    int tile = blockIdx.x;
    int tileY = tile / tilesX, tileX = tile - tileY * tilesX;
    int b = blockIdx.z;
    int y0 = tileY * 16, x0 = tileX * 16;

    const float* inb = in + (size_t)b * 3 * Hin * Win;
    for (int i = t; i < 972; i += 256) {
        int ic = i / 324, rem = i - ic * 324;
        int r = rem / 18, c = rem - r * 18;
        int gy = y0 + r, gx = x0 + c;
        float v = 0.f;
        if (gy < Hin && gx < Win) v = inb[((size_t)ic * Hin + gy) * Win + gx];
        __hip_bfloat16 hv = __float2bfloat16(v);
        xs[i] = *(unsigned short*)&hv;
    }
    __syncthreads();

    int lane = t & 63, wv = t >> 6;
    int l15 = lane & 15, l4 = lane >> 4;

    // A fragments: 4 oc-blocks of 16; row = l15, k-slice = l4*8 + j
    bf16x8 af[4];
#pragma unroll
    for (int m = 0; m < 4; ++m)
        af[m] = *(const bf16x8*)&w1t[((size_t)(m * 16 + l15)) * 32 + l4 * 8];

    // per-j LDS offsets (depend only on l4): k = l4*8+j -> ic,ky,kx
    int off0, off1, off2, off3, off4, off5, off6, off7;
    int ok0, ok1, ok2, ok3, ok4, ok5, ok6, ok7;
#define MKOFF(J) { int kk = l4 * 8 + J; int ic = kk / 9; int r9 = kk - ic * 9; \
                   int ky = r9 / 3; int kx = r9 - ky * 3; \
                   ok##J = (kk < 27); off##J = ok##J ? (ic * 324 + ky * 18 + kx) : 0; }
    MKOFF(0) MKOFF(1) MKOFF(2) MKOFF(3) MKOFF(4) MKOFF(5) MKOFF(6) MKOFF(7)
#undef MKOFF

    f32x4 acc[4][4];   // [oc-block m][row n]
#pragma unroll
    for (int m = 0; m < 4; ++m)
#pragma unroll
        for (int n = 0; n < 4; ++n) acc[m][n] = (f32x4)(0.f);

#pragma unroll
    for (int n = 0; n < 4; ++n) {
        int y = wv * 4 + n;
        int base = y * 18 + l15;
        bf16x8 bfr;
        bfr[0] = ok0 ? (short)xs[base + off0] : (short)0;
        bfr[1] = ok1 ? (short)xs[base + off1] : (short)0;
        bfr[2] = ok2 ? (short)xs[base + off2] : (short)0;
        bfr[3] = ok3 ? (short)xs[base + off3] : (short)0;
        bfr[4] = ok4 ? (short)xs[base + off4] : (short)0;
        bfr[5] = ok5 ? (short)xs[base + off5] : (short)0;
        bfr[6] = ok6 ? (short)xs[base + off6] : (short)0;
        bfr[7] = ok7 ? (short)xs[base + off7] : (short)0;
#pragma unroll
        for (int m = 0; m < 4; ++m)
            acc[m][n] = __builtin_amdgcn_mfma_f32_16x16x32_bf16(af[m], bfr, acc[m][n], 0, 0, 0);
    }

    // epilogue: pool 2x2 (n-pairs vertical, lane-pairs horizontal) + bias + relu
    int qx = tileX * 8 + (l15 >> 1);
    bool xok = ((lane & 1) == 0) && (qx < PW);
#pragma unroll
    for (int m = 0; m < 4; ++m) {
        int ocb = m * 16 + l4 * 4;
#pragma unroll
        for (int np = 0; np < 2; ++np) {
            int qy = tileY * 8 + wv * 2 + np;
            union { __hip_bfloat16 h[4]; uint2 v; } pk;
#pragma unroll
            for (int r = 0; r < 4; ++r) {
                float v = fmaxf(acc[m][2 * np][r], acc[m][2 * np + 1][r]);
                v = fmaxf(v, __shfl_xor(v, 1));
                pk.h[r] = __float2bfloat16(fmaxf(v + bias[ocb + r], 0.f));
            }
            if (xok && qy < PH)
                *(uint2*)&out[(((size_t)b * PH + qy) * PW + qx) * 64 + ocb] = pk.v;
        }
    }
}

// ---------------- conv2 implicit-GEMM on MFMA + fused bias/relu/maxpool, f16 out -
__global__ void conv2_mfma(const __hip_bfloat16* __restrict__ xin,
                           const __hip_bfloat16* __restrict__ wt,
                           const float* __restrict__ bias, __half* __restrict__ out,
                           int H1, int W1, int PH, int PW, int tilesX) {
    __shared__ uint4 xl4[10 * 18 * 8];   // 23040 B; reused as store buffer

    int t = threadIdx.x;
    int tile = blockIdx.x;
    int tileY = tile / tilesX, tileX = tile - tileY * tilesX;
    int b = blockIdx.z;
    int y0 = tileY * 8, x0 = tileX * 16;

    const __hip_bfloat16* xb = xin + (size_t)b * H1 * W1 * 64;
    for (int s = t; s < 1440; s += 256) {
        int pixel = s >> 3, si = s & 7;
        int row = pixel / 18, col = pixel - row * 18;
        int gy = y0 + row, gx = x0 + col;
        uint4 v = make_uint4(0, 0, 0, 0);
        if (gy < H1 && gx < W1)
            v = *(const uint4*)&xb[((size_t)gy * W1 + gx) * 64 + si * 8];
        xl4[(pixel << 3) | (si ^ (col & 7))] = v;
    }
    __syncthreads();

    int lane = t & 63;
    int wid = t >> 6;
    int wr = wid >> 1;
    int wc = wid & 1;
    int l15 = lane & 15, l4 = lane >> 4;

    f32x4 acc[4][4];
#pragma unroll
    for (int m = 0; m < 4; ++m)
#pragma unroll
        for (int n = 0; n < 4; ++n) acc[m][n] = (f32x4)(0.f);

    const __hip_bfloat16* abase = wt + ((size_t)(wr * 64 + l15)) * 576 + l4 * 8;

#pragma unroll
    for (int kk = 0; kk < 9; ++kk) {
        const int ky = kk / 3, kx = kk - ky * 3;
        const int col = l15 + kx;
        const int csw = col & 7;
#pragma unroll
        for (int h = 0; h < 2; ++h) {
            const int k0 = kk * 64 + h * 32;
            bf16x8 af[4], bfv[4];
#pragma unroll
            for (int m = 0; m < 4; ++m)
                af[m] = *(const bf16x8*)(abase + m * 16 * 576 + k0);
            const int sidx = (h * 4 + l4) ^ csw;
#pragma unroll
            for (int n = 0; n < 4; ++n) {
                int row = wc * 4 + n + ky;
                bfv[n] = *(const bf16x8*)&xl4[((row * 18 + col) << 3) | sidx];
            }
#pragma unroll
            for (int m = 0; m < 4; ++m)
#pragma unroll
                for (int n = 0; n < 4; ++n)
                    acc[m][n] = __builtin_amdgcn_mfma_f32_16x16x32_bf16(
                        af[m], bfv[n], acc[m][n], 0, 0, 0);
        }
    }

    __syncthreads();
    __half* plds = (__half*)xl4;
#pragma unroll
    for (int m = 0; m < 4; ++m) {
        int ocb = wr * 64 + m * 16 + l4 * 4;
#pragma unroll
        for (int np = 0; np < 2; ++np) {
            int qyl = wc * 2 + np;
#pragma unroll
            for (int r = 0; r < 4; ++r) {
                float v = fmaxf(acc[m][2 * np][r], acc[m][2 * np + 1][r]);
                v = fmaxf(v, __shfl_xor(v, 1));
                if ((lane & 1) == 0) {
                    float u = fmaxf(v + bias[ocb + r], 0.f);
                    plds[((ocb + r) * 4 + qyl) * 8 + (l15 >> 1)] = __float2half(u);
                }
            }
        }
    }
    __syncthreads();

    int qx0 = tileX * 8, qy0 = tileY * 4;
    for (int i = t; i < 512; i += 256) {
        int oc = i >> 2, qy = i & 3;
        int gqy = qy0 + qy;
        if (gqy < PH) {
            __half* dst = out + (((size_t)b * 128 + oc) * PH + gqy) * PW + qx0;
            const __half* src = &plds[i * 8];
            if (qx0 + 8 <= PW) {
                *(uint4*)dst = *(const uint4*)src;
            } else {
                for (int q = 0; q < 8 && qx0 + q < PW; ++q) dst[q] = src[q];
            }
        }
    }
}

// ---------------- fused dual depthwise xcorr, packed f16 dot2 --------------------
__global__ void xcorr_dual(const __half* __restrict__ x, const __half* __restrict__ k1,
                           const __half* __restrict__ k2,
                           float* __restrict__ out1, float* __restrict__ out2) {
    __shared__ __half xl[62 * 66 + 8];
    __shared__ unsigned kl[224];
    int bc = blockIdx.x;
    int t = threadIdx.x;

    const unsigned* xp = (const unsigned*)(x + (size_t)bc * 3844);
    unsigned* xld = (unsigned*)xl;
    for (int d = t; d < 1922; d += 384) {
        int r = d / 31, c2 = d - r * 31;
        xld[r * 33 + c2] = xp[d];
    }
    if (t < 98) {
        int ky = t / 7, p = t - ky * 7;
        kl[ky * 8 + p] = ((const unsigned*)(k1 + (size_t)bc * 196))[t];
    } else if (t < 196) {
        int i = t - 98;
        int ky = i / 7, p = i - ky * 7;
        kl[112 + ky * 8 + p] = ((const unsigned*)(k2 + (size_t)bc * 196))[i];
    }
    __syncthreads();

    if (t >= 343) return;
    int py = t % 49;
    int px0 = (t / 49) * 8;

    float a10 = 0.f, a11 = 0.f, a12 = 0.f, a13 = 0.f;
    float a14 = 0.f, a15 = 0.f, a16 = 0.f, a17 = 0.f;
    float a20 = 0.f, a21 = 0.f, a22 = 0.f, a23 = 0.f;
    float a24 = 0.f, a25 = 0.f, a26 = 0.f, a27 = 0.f;

    for (int ky = 0; ky < 14; ++ky) {
        const unsigned* row = (const unsigned*)&xl[(py + ky) * 66 + px0];
        unsigned e0 = row[0], e1 = row[1], e2 = row[2], e3 = row[3], e4 = row[4];
        unsigned e5 = row[5], e6 = row[6], e7 = row[7], e8 = row[8], e9 = row[9];
        unsigned e10 = row[10];
        unsigned o0 = (e0 >> 16) | (e1 << 16);
        unsigned o1 = (e1 >> 16) | (e2 << 16);
        unsigned o2 = (e2 >> 16) | (e3 << 16);
        unsigned o3 = (e3 >> 16) | (e4 << 16);
        unsigned o4 = (e4 >> 16) | (e5 << 16);
        unsigned o5 = (e5 >> 16) | (e6 << 16);
        unsigned o6 = (e6 >> 16) | (e7 << 16);
        unsigned o7 = (e7 >> 16) | (e8 << 16);
        unsigned o8 = (e8 >> 16) | (e9 << 16);
        unsigned o9 = (e9 >> 16) | (e10 << 16);
        int kb = ky * 8;
#define PSTEP(P, EA, OA, EB, OB, EC, OC, ED, OD) do { \
        unsigned kp1 = kl[kb + (P)]; unsigned kp2 = kl[kb + 112 + (P)]; \
        a10 = dot2f16(kp1, EA, a10); a20 = dot2f16(kp2, EA, a20); \
        a11 = dot2f16(kp1, OA, a11); a21 = dot2f16(kp2, OA, a21); \
        a12 = dot2f16(kp1, EB, a12); a22 = dot2f16(kp2, EB, a22); \
        a13 = dot2f16(kp1, OB, a13); a23 = dot2f16(kp2, OB, a23); \
        a14 = dot2f16(kp1, EC, a14); a24 = dot2f16(kp2, EC, a24); \
        a15 = dot2f16(kp1, OC, a15); a25 = dot2f16(kp2, OC, a25); \
        a16 = dot2f16(kp1, ED, a16); a26 = dot2f16(kp2, ED, a26); \
        a17 = dot2f16(kp1, OD, a17); a27 = dot2f16(kp2, OD, a27); \
        } while (0)
        PSTEP(0, e0, o0, e1, o1, e2, o2, e3, o3);
        PSTEP(1, e1, o1, e2, o2, e3, o3, e4, o4);
        PSTEP(2, e2, o2, e3, o3, e4, o4, e5, o5);
        PSTEP(3, e3, o3, e4, o4, e5, o5, e6, o6);
        PSTEP(4, e4, o4, e5, o5, e6, o6, e7, o7);
        PSTEP(5, e5, o5, e6, o6, e7, o7, e8, o8);
        PSTEP(6, e6, o6, e7, o7, e8, o8, e9, o9);
#undef PSTEP
    }

    size_t ob = (size_t)bc * 2401 + (size_t)py * 49 + px0;
    out1[ob] = a10; out2[ob] = a20;
    if (px0 < 48) {
        out1[ob + 1] = a11; out1[ob + 2] = a12; out1[ob + 3] = a13;
        out1[ob + 4] = a14; out1[ob + 5] = a15; out1[ob + 6] = a16; out1[ob + 7] = a17;
        out2[ob + 1] = a21; out2[ob + 2] = a22; out2[ob + 3] = a23;
        out2[ob + 4] = a24; out2[ob + 5] = a25; out2[ob + 6] = a26; out2[ob + 7] = a27;
    }
}

extern "C" void kernel_launch(void* const* d_in, const int* in_sizes, int n_in,
                              void* d_out, int out_size, void* d_ws, size_t ws_size,
                              hipStream_t stream) {
    const float* img = (const float*)d_in[0];
    const float* t1  = (const float*)d_in[1];
    const float* t2  = (const float*)d_in[2];
    const float* w1  = (const float*)d_in[3];
    const float* b1  = (const float*)d_in[4];
    const float* w2  = (const float*)d_in[5];
    const float* b2  = (const float*)d_in[6];
    float* out = (float*)d_out;

    char* ws = (char*)d_ws;
    __hip_bfloat16* bufA = (__hip_bfloat16*)ws;                 // 32*127*127*64*2 = 66,064,384
    __hip_bfloat16* w1t  = (__hip_bfloat16*)(ws + 66064384);    // 64*32*2 = 4,096
    __hip_bfloat16* w2t  = (__hip_bfloat16*)(ws + 66068480);    // 128*576*2 = 147,456
    __half* xf = (__half*)(ws + 66215936);                      // 31,490,048
    __half* k1 = (__half*)(ws + 97705984);                      // 1,605,632
    __half* k2 = (__half*)(ws + 99311616);                      // end 100,917,248

    wt_xform_all<<<296, 256, 0, stream>>>(w1, w2, w1t, w2t);

    // Image path, full 32-batch dispatches
    conv1_mfma<<<dim3(256, 1, 32), 256, 0, stream>>>(img, w1t, b1, bufA,
                                                     256, 256, 127, 127, 16);
    conv2_mfma<<<dim3(128, 1, 32), 256, 0, stream>>>(bufA, w2t, b2, xf,
                                                     127, 127, 62, 62, 8);

    // Template paths
    conv1_mfma<<<dim3(16, 1, 32), 256, 0, stream>>>(t1, w1t, b1, bufA,
                                                    64, 64, 31, 31, 4);
    conv2_mfma<<<dim3(8, 1, 32), 256, 0, stream>>>(bufA, w2t, b2, k1,
                                                   31, 31, 14, 14, 2);
    conv1_mfma<<<dim3(16, 1, 32), 256, 0, stream>>>(t2, w1t, b1, bufA,
                                                    64, 64, 31, 31, 4);
    conv2_mfma<<<dim3(8, 1, 32), 256, 0, stream>>>(bufA, w2t, b2, k2,
                                                   31, 31, 14, 14, 2);

    xcorr_dual<<<4096, 384, 0, stream>>>(xf, k1, k2, out, out + (size_t)9834496);
}

// Round 6
// 414.567 us; speedup vs baseline: 22.3838x; 1.2008x over previous
//
#include <hip/hip_runtime.h>
#include <hip/hip_bf16.h>
#include <hip/hip_fp16.h>

typedef __attribute__((ext_vector_type(8))) short bf16x8;
typedef __attribute__((ext_vector_type(4))) float f32x4;
typedef __attribute__((ext_vector_type(2))) _Float16 f16x2;

__device__ __forceinline__ float dot2f16(unsigned a, unsigned b, float c) {
#if __has_builtin(__builtin_amdgcn_fdot2)
    return __builtin_amdgcn_fdot2(__builtin_bit_cast(f16x2, a),
                                  __builtin_bit_cast(f16x2, b), c, false);
#else
    union { unsigned u; __half2 h; } ua, ub;
    ua.u = a; ub.u = b;
    return c + __low2float(ua.h) * __low2float(ub.h)
             + __high2float(ua.h) * __high2float(ub.h);
#endif
}

// ---------------- weight transforms -------------------------------------------
__global__ void wt_xform_all(const float* __restrict__ w1, const float* __restrict__ w2,
                             __hip_bfloat16* __restrict__ w1t, __hip_bfloat16* __restrict__ w2t) {
    int i = blockIdx.x * 256 + threadIdx.x;
    if (i < 2048) {
        int oc = i >> 5, k = i & 31;
        w1t[i] = (k < 27) ? __float2bfloat16(w1[oc * 27 + k]) : __float2bfloat16(0.f);
        return;
    }
    int j = i - 2048;
    if (j < 128 * 576) {
        int oc = j / 576, k = j - oc * 576;
        int kk = k >> 6, ic = k & 63;
        int ky = kk / 3, kx = kk - ky * 3;
        w2t[j] = __float2bfloat16(w2[(((size_t)oc * 64 + ic) * 3 + ky) * 3 + kx]);
    }
}

// ---------------- conv1 implicit-GEMM on MFMA + fused bias/relu/maxpool ---------
// __launch_bounds__(256,2): without it hipcc caps VGPRs at 64 (assumes 1024-thr
// blocks) and spills the 64-reg f32x4 acc[4][4] to scratch (R5: 400MB phantom HBM).
__global__ void __launch_bounds__(256, 2)
conv1_mfma(const float* __restrict__ in,
           const __hip_bfloat16* __restrict__ w1t,
           const float* __restrict__ bias,
           __hip_bfloat16* __restrict__ out,
           int Hin, int Win, int PH, int PW, int tilesX) {
    __shared__ unsigned short xs[3 * 324];   // [ic][18 rows][18 cols] bf16 bits
    int t = threadIdx.x;
    int tile = blockIdx.x;
    int tileY = tile / tilesX, tileX = tile - tileY * tilesX;
    int b = blockIdx.z;
    int y0 = tileY * 16, x0 = tileX * 16;

    const float* inb = in + (size_t)b * 3 * Hin * Win;
    for (int i = t; i < 972; i += 256) {
        int ic = i / 324, rem = i - ic * 324;
        int r = rem / 18, c = rem - r * 18;
        int gy = y0 + r, gx = x0 + c;
        float v = 0.f;
        if (gy < Hin && gx < Win) v = inb[((size_t)ic * Hin + gy) * Win + gx];
        __hip_bfloat16 hv = __float2bfloat16(v);
        xs[i] = *(unsigned short*)&hv;
    }
    __syncthreads();

    int lane = t & 63, wv = t >> 6;
    int l15 = lane & 15, l4 = lane >> 4;

    bf16x8 af[4];
#pragma unroll
    for (int m = 0; m < 4; ++m)
        af[m] = *(const bf16x8*)&w1t[((size_t)(m * 16 + l15)) * 32 + l4 * 8];

    int off0, off1, off2, off3, off4, off5, off6, off7;
    int ok0, ok1, ok2, ok3, ok4, ok5, ok6, ok7;
#define MKOFF(J) { int kk = l4 * 8 + J; int ic = kk / 9; int r9 = kk - ic * 9; \
                   int ky = r9 / 3; int kx = r9 - ky * 3; \
                   ok##J = (kk < 27); off##J = ok##J ? (ic * 324 + ky * 18 + kx) : 0; }
    MKOFF(0) MKOFF(1) MKOFF(2) MKOFF(3) MKOFF(4) MKOFF(5) MKOFF(6) MKOFF(7)
#undef MKOFF

    f32x4 acc[4][4];
#pragma unroll
    for (int m = 0; m < 4; ++m)
#pragma unroll
        for (int n = 0; n < 4; ++n) acc[m][n] = (f32x4)(0.f);

#pragma unroll
    for (int n = 0; n < 4; ++n) {
        int y = wv * 4 + n;
        int base = y * 18 + l15;
        bf16x8 bfr;
        bfr[0] = ok0 ? (short)xs[base + off0] : (short)0;
        bfr[1] = ok1 ? (short)xs[base + off1] : (short)0;
        bfr[2] = ok2 ? (short)xs[base + off2] : (short)0;
        bfr[3] = ok3 ? (short)xs[base + off3] : (short)0;
        bfr[4] = ok4 ? (short)xs[base + off4] : (short)0;
        bfr[5] = ok5 ? (short)xs[base + off5] : (short)0;
        bfr[6] = ok6 ? (short)xs[base + off6] : (short)0;
        bfr[7] = ok7 ? (short)xs[base + off7] : (short)0;
#pragma unroll
        for (int m = 0; m < 4; ++m)
            acc[m][n] = __builtin_amdgcn_mfma_f32_16x16x32_bf16(af[m], bfr, acc[m][n], 0, 0, 0);
    }

    int qx = tileX * 8 + (l15 >> 1);
    bool xok = ((lane & 1) == 0) && (qx < PW);
#pragma unroll
    for (int m = 0; m < 4; ++m) {
        int ocb = m * 16 + l4 * 4;
#pragma unroll
        for (int np = 0; np < 2; ++np) {
            int qy = tileY * 8 + wv * 2 + np;
            union { __hip_bfloat16 h[4]; uint2 v; } pk;
#pragma unroll
            for (int r = 0; r < 4; ++r) {
                float v = fmaxf(acc[m][2 * np][r], acc[m][2 * np + 1][r]);
                v = fmaxf(v, __shfl_xor(v, 1));
                pk.h[r] = __float2bfloat16(fmaxf(v + bias[ocb + r], 0.f));
            }
            if (xok && qy < PH)
                *(uint2*)&out[(((size_t)b * PH + qy) * PW + qx) * 64 + ocb] = pk.v;
        }
    }
}

// ---------------- conv2 implicit-GEMM on MFMA + fused bias/relu/maxpool, f16 out -
__global__ void __launch_bounds__(256, 2)
conv2_mfma(const __hip_bfloat16* __restrict__ xin,
           const __hip_bfloat16* __restrict__ wt,
           const float* __restrict__ bias, __half* __restrict__ out,
           int H1, int W1, int PH, int PW, int tilesX) {
    __shared__ uint4 xl4[10 * 18 * 8];   // 23040 B; reused as store buffer

    int t = threadIdx.x;
    int tile = blockIdx.x;
    int tileY = tile / tilesX, tileX = tile - tileY * tilesX;
    int b = blockIdx.z;
    int y0 = tileY * 8, x0 = tileX * 16;

    const __hip_bfloat16* xb = xin + (size_t)b * H1 * W1 * 64;
    for (int s = t; s < 1440; s += 256) {
        int pixel = s >> 3, si = s & 7;
        int row = pixel / 18, col = pixel - row * 18;
        int gy = y0 + row, gx = x0 + col;
        uint4 v = make_uint4(0, 0, 0, 0);
        if (gy < H1 && gx < W1)
            v = *(const uint4*)&xb[((size_t)gy * W1 + gx) * 64 + si * 8];
        xl4[(pixel << 3) | (si ^ (col & 7))] = v;
    }
    __syncthreads();

    int lane = t & 63;
    int wid = t >> 6;
    int wr = wid >> 1;
    int wc = wid & 1;
    int l15 = lane & 15, l4 = lane >> 4;

    f32x4 acc[4][4];
#pragma unroll
    for (int m = 0; m < 4; ++m)
#pragma unroll
        for (int n = 0; n < 4; ++n) acc[m][n] = (f32x4)(0.f);

    const __hip_bfloat16* abase = wt + ((size_t)(wr * 64 + l15)) * 576 + l4 * 8;

#pragma unroll
    for (int kk = 0; kk < 9; ++kk) {
        const int ky = kk / 3, kx = kk - ky * 3;
        const int col = l15 + kx;
        const int csw = col & 7;
#pragma unroll
        for (int h = 0; h < 2; ++h) {
            const int k0 = kk * 64 + h * 32;
            bf16x8 af[4], bfv[4];
#pragma unroll
            for (int m = 0; m < 4; ++m)
                af[m] = *(const bf16x8*)(abase + m * 16 * 576 + k0);
            const int sidx = (h * 4 + l4) ^ csw;
#pragma unroll
            for (int n = 0; n < 4; ++n) {
                int row = wc * 4 + n + ky;
                bfv[n] = *(const bf16x8*)&xl4[((row * 18 + col) << 3) | sidx];
            }
#pragma unroll
            for (int m = 0; m < 4; ++m)
#pragma unroll
                for (int n = 0; n < 4; ++n)
                    acc[m][n] = __builtin_amdgcn_mfma_f32_16x16x32_bf16(
                        af[m], bfv[n], acc[m][n], 0, 0, 0);
        }
    }

    __syncthreads();
    __half* plds = (__half*)xl4;
#pragma unroll
    for (int m = 0; m < 4; ++m) {
        int ocb = wr * 64 + m * 16 + l4 * 4;
#pragma unroll
        for (int np = 0; np < 2; ++np) {
            int qyl = wc * 2 + np;
#pragma unroll
            for (int r = 0; r < 4; ++r) {
                float v = fmaxf(acc[m][2 * np][r], acc[m][2 * np + 1][r]);
                v = fmaxf(v, __shfl_xor(v, 1));
                if ((lane & 1) == 0) {
                    float u = fmaxf(v + bias[ocb + r], 0.f);
                    plds[((ocb + r) * 4 + qyl) * 8 + (l15 >> 1)] = __float2half(u);
                }
            }
        }
    }
    __syncthreads();

    int qx0 = tileX * 8, qy0 = tileY * 4;
    for (int i = t; i < 512; i += 256) {
        int oc = i >> 2, qy = i & 3;
        int gqy = qy0 + qy;
        if (gqy < PH) {
            __half* dst = out + (((size_t)b * 128 + oc) * PH + gqy) * PW + qx0;
            const __half* src = &plds[i * 8];
            if (qx0 + 8 <= PW) {
                *(uint4*)dst = *(const uint4*)src;
            } else {
                for (int q = 0; q < 8 && qx0 + q < PW; ++q) dst[q] = src[q];
            }
        }
    }
}

// ---------------- fused dual depthwise xcorr, packed f16 dot2 --------------------
__global__ void xcorr_dual(const __half* __restrict__ x, const __half* __restrict__ k1,
                           const __half* __restrict__ k2,
                           float* __restrict__ out1, float* __restrict__ out2) {
    __shared__ __half xl[62 * 66 + 8];
    __shared__ unsigned kl[224];
    int bc = blockIdx.x;
    int t = threadIdx.x;

    const unsigned* xp = (const unsigned*)(x + (size_t)bc * 3844);
    unsigned* xld = (unsigned*)xl;
    for (int d = t; d < 1922; d += 384) {
        int r = d / 31, c2 = d - r * 31;
        xld[r * 33 + c2] = xp[d];
    }
    if (t < 98) {
        int ky = t / 7, p = t - ky * 7;
        kl[ky * 8 + p] = ((const unsigned*)(k1 + (size_t)bc * 196))[t];
    } else if (t < 196) {
        int i = t - 98;
        int ky = i / 7, p = i - ky * 7;
        kl[112 + ky * 8 + p] = ((const unsigned*)(k2 + (size_t)bc * 196))[i];
    }
    __syncthreads();

    if (t >= 343) return;
    int py = t % 49;
    int px0 = (t / 49) * 8;

    float a10 = 0.f, a11 = 0.f, a12 = 0.f, a13 = 0.f;
    float a14 = 0.f, a15 = 0.f, a16 = 0.f, a17 = 0.f;
    float a20 = 0.f, a21 = 0.f, a22 = 0.f, a23 = 0.f;
    float a24 = 0.f, a25 = 0.f, a26 = 0.f, a27 = 0.f;

    for (int ky = 0; ky < 14; ++ky) {
        const unsigned* row = (const unsigned*)&xl[(py + ky) * 66 + px0];
        unsigned e0 = row[0], e1 = row[1], e2 = row[2], e3 = row[3], e4 = row[4];
        unsigned e5 = row[5], e6 = row[6], e7 = row[7], e8 = row[8], e9 = row[9];
        unsigned e10 = row[10];
        unsigned o0 = (e0 >> 16) | (e1 << 16);
        unsigned o1 = (e1 >> 16) | (e2 << 16);
        unsigned o2 = (e2 >> 16) | (e3 << 16);
        unsigned o3 = (e3 >> 16) | (e4 << 16);
        unsigned o4 = (e4 >> 16) | (e5 << 16);
        unsigned o5 = (e5 >> 16) | (e6 << 16);
        unsigned o6 = (e6 >> 16) | (e7 << 16);
        unsigned o7 = (e7 >> 16) | (e8 << 16);
        unsigned o8 = (e8 >> 16) | (e9 << 16);
        unsigned o9 = (e9 >> 16) | (e10 << 16);
        int kb = ky * 8;
#define PSTEP(P, EA, OA, EB, OB, EC, OC, ED, OD) do { \
        unsigned kp1 = kl[kb + (P)]; unsigned kp2 = kl[kb + 112 + (P)]; \
        a10 = dot2f16(kp1, EA, a10); a20 = dot2f16(kp2, EA, a20); \
        a11 = dot2f16(kp1, OA, a11); a21 = dot2f16(kp2, OA, a21); \
        a12 = dot2f16(kp1, EB, a12); a22 = dot2f16(kp2, EB, a22); \
        a13 = dot2f16(kp1, OB, a13); a23 = dot2f16(kp2, OB, a23); \
        a14 = dot2f16(kp1, EC, a14); a24 = dot2f16(kp2, EC, a24); \
        a15 = dot2f16(kp1, OC, a15); a25 = dot2f16(kp2, OC, a25); \
        a16 = dot2f16(kp1, ED, a16); a26 = dot2f16(kp2, ED, a26); \
        a17 = dot2f16(kp1, OD, a17); a27 = dot2f16(kp2, OD, a27); \
        } while (0)
        PSTEP(0, e0, o0, e1, o1, e2, o2, e3, o3);
        PSTEP(1, e1, o1, e2, o2, e3, o3, e4, o4);
        PSTEP(2, e2, o2, e3, o3, e4, o4, e5, o5);
        PSTEP(3, e3, o3, e4, o4, e5, o5, e6, o6);
        PSTEP(4, e4, o4, e5, o5, e6, o6, e7, o7);
        PSTEP(5, e5, o5, e6, o6, e7, o7, e8, o8);
        PSTEP(6, e6, o6, e7, o7, e8, o8, e9, o9);
#undef PSTEP
    }

    size_t ob = (size_t)bc * 2401 + (size_t)py * 49 + px0;
    out1[ob] = a10; out2[ob] = a20;
    if (px0 < 48) {
        out1[ob + 1] = a11; out1[ob + 2] = a12; out1[ob + 3] = a13;
        out1[ob + 4] = a14; out1[ob + 5] = a15; out1[ob + 6] = a16; out1[ob + 7] = a17;
        out2[ob + 1] = a21; out2[ob + 2] = a22; out2[ob + 3] = a23;
        out2[ob + 4] = a24; out2[ob + 5] = a25; out2[ob + 6] = a26; out2[ob + 7] = a27;
    }
}

extern "C" void kernel_launch(void* const* d_in, const int* in_sizes, int n_in,
                              void* d_out, int out_size, void* d_ws, size_t ws_size,
                              hipStream_t stream) {
    const float* img = (const float*)d_in[0];
    const float* t1  = (const float*)d_in[1];
    const float* t2  = (const float*)d_in[2];
    const float* w1  = (const float*)d_in[3];
    const float* b1  = (const float*)d_in[4];
    const float* w2  = (const float*)d_in[5];
    const float* b2  = (const float*)d_in[6];
    float* out = (float*)d_out;

    char* ws = (char*)d_ws;
    __hip_bfloat16* bufA = (__hip_bfloat16*)ws;                 // 66,064,384 B
    __hip_bfloat16* w1t  = (__hip_bfloat16*)(ws + 66064384);    // 4,096 B
    __hip_bfloat16* w2t  = (__hip_bfloat16*)(ws + 66068480);    // 147,456 B
    __half* xf = (__half*)(ws + 66215936);                      // 31,490,048
    __half* k1 = (__half*)(ws + 97705984);                      // 1,605,632
    __half* k2 = (__half*)(ws + 99311616);                      // end 100,917,248

    wt_xform_all<<<296, 256, 0, stream>>>(w1, w2, w1t, w2t);

    conv1_mfma<<<dim3(256, 1, 32), 256, 0, stream>>>(img, w1t, b1, bufA,
                                                     256, 256, 127, 127, 16);
    conv2_mfma<<<dim3(128, 1, 32), 256, 0, stream>>>(bufA, w2t, b2, xf,
                                                     127, 127, 62, 62, 8);

    conv1_mfma<<<dim3(16, 1, 32), 256, 0, stream>>>(t1, w1t, b1, bufA,
                                                    64, 64, 31, 31, 4);
    conv2_mfma<<<dim3(8, 1, 32), 256, 0, stream>>>(bufA, w2t, b2, k1,
                                                   31, 31, 14, 14, 2);
    conv1_mfma<<<dim3(16, 1, 32), 256, 0, stream>>>(t2, w1t, b1, bufA,
                                                    64, 64, 31, 31, 4);
    conv2_mfma<<<dim3(8, 1, 32), 256, 0, stream>>>(bufA, w2t, b2, k2,
                                                   31, 31, 14, 14, 2);

    xcorr_dual<<<4096, 384, 0, stream>>>(xf, k1, k2, out, out + (size_t)9834496);
}

// Round 7
// 334.164 us; speedup vs baseline: 27.7696x; 1.2406x over previous
//
#include <hip/hip_runtime.h>
#include <hip/hip_bf16.h>
#include <hip/hip_fp16.h>

typedef __attribute__((ext_vector_type(8))) short bf16x8;
typedef __attribute__((ext_vector_type(4))) float f32x4;
typedef __attribute__((ext_vector_type(2))) _Float16 f16x2;

__device__ __forceinline__ float dot2f16(unsigned a, unsigned b, float c) {
#if __has_builtin(__builtin_amdgcn_fdot2)
    return __builtin_amdgcn_fdot2(__builtin_bit_cast(f16x2, a),
                                  __builtin_bit_cast(f16x2, b), c, false);
#else
    union { unsigned u; __half2 h; } ua, ub;
    ua.u = a; ub.u = b;
    return c + __low2float(ua.h) * __low2float(ub.h)
             + __high2float(ua.h) * __high2float(ub.h);
#endif
}

// ---------------- weight transforms -------------------------------------------
// w1 [64][3][3][3] f32 -> w1t [64][32] bf16 (k = ic*9+ky*3+kx, pad 27..31 = 0)
// w2 [128][64][3][3] f32 -> w2k [9][128][64] bf16  (kk = ky*3+kx panels)
__global__ void wt_xform_all(const float* __restrict__ w1, const float* __restrict__ w2,
                             __hip_bfloat16* __restrict__ w1t, __hip_bfloat16* __restrict__ w2k) {
    int i = blockIdx.x * 256 + threadIdx.x;
    if (i < 2048) {
        int oc = i >> 5, k = i & 31;
        w1t[i] = (k < 27) ? __float2bfloat16(w1[oc * 27 + k]) : __float2bfloat16(0.f);
        return;
    }
    int j = i - 2048;
    if (j < 9 * 128 * 64) {
        int kk = j >> 13, r = j & 8191;
        int oc = r >> 6, ic = r & 63;
        int ky = kk / 3, kx = kk - ky * 3;
        w2k[j] = __float2bfloat16(w2[(((size_t)oc * 64 + ic) * 3 + ky) * 3 + kx]);
    }
}

// ---------------- conv1 implicit-GEMM on MFMA + fused bias/relu/maxpool ---------
__global__ void __launch_bounds__(256, 2)
conv1_mfma(const float* __restrict__ in,
           const __hip_bfloat16* __restrict__ w1t,
           const float* __restrict__ bias,
           __hip_bfloat16* __restrict__ out,
           int Hin, int Win, int PH, int PW, int tilesX) {
    __shared__ unsigned short xs[3 * 324];   // [ic][18 rows][18 cols] bf16 bits
    int t = threadIdx.x;
    int tile = blockIdx.x;
    int tileY = tile / tilesX, tileX = tile - tileY * tilesX;
    int b = blockIdx.z;
    int y0 = tileY * 16, x0 = tileX * 16;

    const float* inb = in + (size_t)b * 3 * Hin * Win;
    for (int i = t; i < 972; i += 256) {
        int ic = i / 324, rem = i - ic * 324;
        int r = rem / 18, c = rem - r * 18;
        int gy = y0 + r, gx = x0 + c;
        float v = 0.f;
        if (gy < Hin && gx < Win) v = inb[((size_t)ic * Hin + gy) * Win + gx];
        __hip_bfloat16 hv = __float2bfloat16(v);
        xs[i] = *(unsigned short*)&hv;
    }
    __syncthreads();

    int lane = t & 63, wv = t >> 6;
    int l15 = lane & 15, l4 = lane >> 4;

    bf16x8 af[4];
#pragma unroll
    for (int m = 0; m < 4; ++m)
        af[m] = *(const bf16x8*)&w1t[((size_t)(m * 16 + l15)) * 32 + l4 * 8];

    int off0, off1, off2, off3, off4, off5, off6, off7;
    int ok0, ok1, ok2, ok3, ok4, ok5, ok6, ok7;
#define MKOFF(J) { int kk = l4 * 8 + J; int ic = kk / 9; int r9 = kk - ic * 9; \
                   int ky = r9 / 3; int kx = r9 - ky * 3; \
                   ok##J = (kk < 27); off##J = ok##J ? (ic * 324 + ky * 18 + kx) : 0; }
    MKOFF(0) MKOFF(1) MKOFF(2) MKOFF(3) MKOFF(4) MKOFF(5) MKOFF(6) MKOFF(7)
#undef MKOFF

    f32x4 acc[4][4];
#pragma unroll
    for (int m = 0; m < 4; ++m)
#pragma unroll
        for (int n = 0; n < 4; ++n) acc[m][n] = (f32x4)(0.f);

#pragma unroll
    for (int n = 0; n < 4; ++n) {
        int y = wv * 4 + n;
        int base = y * 18 + l15;
        bf16x8 bfr;
        bfr[0] = ok0 ? (short)xs[base + off0] : (short)0;
        bfr[1] = ok1 ? (short)xs[base + off1] : (short)0;
        bfr[2] = ok2 ? (short)xs[base + off2] : (short)0;
        bfr[3] = ok3 ? (short)xs[base + off3] : (short)0;
        bfr[4] = ok4 ? (short)xs[base + off4] : (short)0;
        bfr[5] = ok5 ? (short)xs[base + off5] : (short)0;
        bfr[6] = ok6 ? (short)xs[base + off6] : (short)0;
        bfr[7] = ok7 ? (short)xs[base + off7] : (short)0;
#pragma unroll
        for (int m = 0; m < 4; ++m)
            acc[m][n] = __builtin_amdgcn_mfma_f32_16x16x32_bf16(af[m], bfr, acc[m][n], 0, 0, 0);
    }

    int qx = tileX * 8 + (l15 >> 1);
    bool xok = ((lane & 1) == 0) && (qx < PW);
#pragma unroll
    for (int m = 0; m < 4; ++m) {
        int ocb = m * 16 + l4 * 4;
#pragma unroll
        for (int np = 0; np < 2; ++np) {
            int qy = tileY * 8 + wv * 2 + np;
            union { __hip_bfloat16 h[4]; uint2 v; } pk;
#pragma unroll
            for (int r = 0; r < 4; ++r) {
                float v = fmaxf(acc[m][2 * np][r], acc[m][2 * np + 1][r]);
                v = fmaxf(v, __shfl_xor(v, 1));
                pk.h[r] = __float2bfloat16(fmaxf(v + bias[ocb + r], 0.f));
            }
            if (xok && qy < PH)
                *(uint2*)&out[(((size_t)b * PH + qy) * PW + qx) * 64 + ocb] = pk.v;
        }
    }
}

// ---------------- conv2 implicit-GEMM: A(weights) LDS double-buffered ------------
// w2k [9][128][64] bf16. Per kk: prefetch next 16KB A-panel (regs, issue-early /
// ds_write-late), compute 32 MFMA/wave from LDS only. A-panel slot-swizzled:
// LDS[oc][slot] = W[oc][slot ^ (oc&7)]; read applies same XOR -> <=2-way conflicts.
__global__ void __launch_bounds__(256, 2)
conv2_mfma(const __hip_bfloat16* __restrict__ xin,
           const __hip_bfloat16* __restrict__ w2k,
           const float* __restrict__ bias, __half* __restrict__ out,
           int H1, int W1, int PH, int PW, int tilesX) {
    __shared__ uint4 xl4[10 * 18 * 8];   // 23040 B input tile; reused as store buffer
    __shared__ uint4 aw[2][1024];        // 2 x 16 KB weight panels

    int t = threadIdx.x;
    int tile = blockIdx.x;
    int tileY = tile / tilesX, tileX = tile - tileY * tilesX;
    int b = blockIdx.z;
    int y0 = tileY * 8, x0 = tileX * 16;

    const __hip_bfloat16* xb = xin + (size_t)b * H1 * W1 * 64;
    for (int s = t; s < 1440; s += 256) {
        int pixel = s >> 3, si = s & 7;
        int row = pixel / 18, col = pixel - row * 18;
        int gy = y0 + row, gx = x0 + col;
        uint4 v = make_uint4(0, 0, 0, 0);
        if (gy < H1 && gx < W1)
            v = *(const uint4*)&xb[((size_t)gy * W1 + gx) * 64 + si * 8];
        xl4[(pixel << 3) | (si ^ (col & 7))] = v;
    }
    // stage A panel kk=0
    {
        const uint4* src = (const uint4*)w2k;
#pragma unroll
        for (int j = 0; j < 4; ++j) {
            int s = t + 256 * j;
            int oc = s >> 3, sl = s & 7;
            aw[0][s] = src[(oc << 3) | (sl ^ (oc & 7))];
        }
    }
    __syncthreads();

    int lane = t & 63;
    int wid = t >> 6;
    int wr = wid >> 1;
    int wc = wid & 1;
    int l15 = lane & 15, l4 = lane >> 4;

    f32x4 acc[4][4];
#pragma unroll
    for (int m = 0; m < 4; ++m)
#pragma unroll
        for (int n = 0; n < 4; ++n) acc[m][n] = (f32x4)(0.f);

    for (int kk = 0; kk < 9; ++kk) {
        const int cur = kk & 1;
        // issue prefetch of next A panel (latency hides under compute below)
        uint4 pf0, pf1, pf2, pf3;
        if (kk < 8) {
            const uint4* src = (const uint4*)(w2k + (size_t)(kk + 1) * 8192);
            int s0 = t,       o0 = s0 >> 3, q0 = s0 & 7;
            int s1 = t + 256, o1 = s1 >> 3, q1 = s1 & 7;
            int s2 = t + 512, o2 = s2 >> 3, q2 = s2 & 7;
            int s3 = t + 768, o3 = s3 >> 3, q3 = s3 & 7;
            pf0 = src[(o0 << 3) | (q0 ^ (o0 & 7))];
            pf1 = src[(o1 << 3) | (q1 ^ (o1 & 7))];
            pf2 = src[(o2 << 3) | (q2 ^ (o2 & 7))];
            pf3 = src[(o3 << 3) | (q3 ^ (o3 & 7))];
        }

        const int ky = kk / 3, kx = kk - ky * 3;
        const int col = l15 + kx;
        const int csw = col & 7;
#pragma unroll
        for (int h = 0; h < 2; ++h) {
            const int c = h * 4 + l4;
            bf16x8 af[4], bfv[4];
#pragma unroll
            for (int m = 0; m < 4; ++m) {
                int oc = wr * 64 + m * 16 + l15;
                af[m] = *(const bf16x8*)&aw[cur][oc * 8 + (c ^ (oc & 7))];
            }
            const int sidx = c ^ csw;
#pragma unroll
            for (int n = 0; n < 4; ++n) {
                int row = wc * 4 + n + ky;
                bfv[n] = *(const bf16x8*)&xl4[((row * 18 + col) << 3) | sidx];
            }
#pragma unroll
            for (int m = 0; m < 4; ++m)
#pragma unroll
                for (int n = 0; n < 4; ++n)
                    acc[m][n] = __builtin_amdgcn_mfma_f32_16x16x32_bf16(
                        af[m], bfv[n], acc[m][n], 0, 0, 0);
        }

        if (kk < 8) {
            aw[cur ^ 1][t]       = pf0;
            aw[cur ^ 1][t + 256] = pf1;
            aw[cur ^ 1][t + 512] = pf2;
            aw[cur ^ 1][t + 768] = pf3;
        }
        __syncthreads();
    }

    // epilogue: pool + bias + relu -> LDS f16 -> contiguous NCHW stores
    __half* plds = (__half*)xl4;
#pragma unroll
    for (int m = 0; m < 4; ++m) {
        int ocb = wr * 64 + m * 16 + l4 * 4;
#pragma unroll
        for (int np = 0; np < 2; ++np) {
            int qyl = wc * 2 + np;
#pragma unroll
            for (int r = 0; r < 4; ++r) {
                float v = fmaxf(acc[m][2 * np][r], acc[m][2 * np + 1][r]);
                v = fmaxf(v, __shfl_xor(v, 1));
                if ((lane & 1) == 0) {
                    float u = fmaxf(v + bias[ocb + r], 0.f);
                    plds[((ocb + r) * 4 + qyl) * 8 + (l15 >> 1)] = __float2half(u);
                }
            }
        }
    }
    __syncthreads();

    int qx0 = tileX * 8, qy0 = tileY * 4;
    for (int i = t; i < 512; i += 256) {
        int oc = i >> 2, qy = i & 3;
        int gqy = qy0 + qy;
        if (gqy < PH) {
            __half* dst = out + (((size_t)b * 128 + oc) * PH + gqy) * PW + qx0;
            const __half* src = &plds[i * 8];
            if (qx0 + 8 <= PW) {
                *(uint4*)dst = *(const uint4*)src;
            } else {
                for (int q = 0; q < 8 && qx0 + q < PW; ++q) dst[q] = src[q];
            }
        }
    }
}

// ---------------- fused dual depthwise xcorr, packed f16 dot2 --------------------
__global__ void xcorr_dual(const __half* __restrict__ x, const __half* __restrict__ k1,
                           const __half* __restrict__ k2,
                           float* __restrict__ out1, float* __restrict__ out2) {
    __shared__ __half xl[62 * 66 + 8];
    __shared__ unsigned kl[224];
    int bc = blockIdx.x;
    int t = threadIdx.x;

    const unsigned* xp = (const unsigned*)(x + (size_t)bc * 3844);
    unsigned* xld = (unsigned*)xl;
    for (int d = t; d < 1922; d += 384) {
        int r = d / 31, c2 = d - r * 31;
        xld[r * 33 + c2] = xp[d];
    }
    if (t < 98) {
        int ky = t / 7, p = t - ky * 7;
        kl[ky * 8 + p] = ((const unsigned*)(k1 + (size_t)bc * 196))[t];
    } else if (t < 196) {
        int i = t - 98;
        int ky = i / 7, p = i - ky * 7;
        kl[112 + ky * 8 + p] = ((const unsigned*)(k2 + (size_t)bc * 196))[i];
    }
    __syncthreads();

    if (t >= 343) return;
    int py = t % 49;
    int px0 = (t / 49) * 8;

    float a10 = 0.f, a11 = 0.f, a12 = 0.f, a13 = 0.f;
    float a14 = 0.f, a15 = 0.f, a16 = 0.f, a17 = 0.f;
    float a20 = 0.f, a21 = 0.f, a22 = 0.f, a23 = 0.f;
    float a24 = 0.f, a25 = 0.f, a26 = 0.f, a27 = 0.f;

    for (int ky = 0; ky < 14; ++ky) {
        const unsigned* row = (const unsigned*)&xl[(py + ky) * 66 + px0];
        unsigned e0 = row[0], e1 = row[1], e2 = row[2], e3 = row[3], e4 = row[4];
        unsigned e5 = row[5], e6 = row[6], e7 = row[7], e8 = row[8], e9 = row[9];
        unsigned e10 = row[10];
        unsigned o0 = (e0 >> 16) | (e1 << 16);
        unsigned o1 = (e1 >> 16) | (e2 << 16);
        unsigned o2 = (e2 >> 16) | (e3 << 16);
        unsigned o3 = (e3 >> 16) | (e4 << 16);
        unsigned o4 = (e4 >> 16) | (e5 << 16);
        unsigned o5 = (e5 >> 16) | (e6 << 16);
        unsigned o6 = (e6 >> 16) | (e7 << 16);
        unsigned o7 = (e7 >> 16) | (e8 << 16);
        unsigned o8 = (e8 >> 16) | (e9 << 16);
        unsigned o9 = (e9 >> 16) | (e10 << 16);
        int kb = ky * 8;
#define PSTEP(P, EA, OA, EB, OB, EC, OC, ED, OD) do { \
        unsigned kp1 = kl[kb + (P)]; unsigned kp2 = kl[kb + 112 + (P)]; \
        a10 = dot2f16(kp1, EA, a10); a20 = dot2f16(kp2, EA, a20); \
        a11 = dot2f16(kp1, OA, a11); a21 = dot2f16(kp2, OA, a21); \
        a12 = dot2f16(kp1, EB, a12); a22 = dot2f16(kp2, EB, a22); \
        a13 = dot2f16(kp1, OB, a13); a23 = dot2f16(kp2, OB, a23); \
        a14 = dot2f16(kp1, EC, a14); a24 = dot2f16(kp2, EC, a24); \
        a15 = dot2f16(kp1, OC, a15); a25 = dot2f16(kp2, OC, a25); \
        a16 = dot2f16(kp1, ED, a16); a26 = dot2f16(kp2, ED, a26); \
        a17 = dot2f16(kp1, OD, a17); a27 = dot2f16(kp2, OD, a27); \
        } while (0)
        PSTEP(0, e0, o0, e1, o1, e2, o2, e3, o3);
        PSTEP(1, e1, o1, e2, o2, e3, o3, e4, o4);
        PSTEP(2, e2, o2, e3, o3, e4, o4, e5, o5);
        PSTEP(3, e3, o3, e4, o4, e5, o5, e6, o6);
        PSTEP(4, e4, o4, e5, o5, e6, o6, e7, o7);
        PSTEP(5, e5, o5, e6, o6, e7, o7, e8, o8);
        PSTEP(6, e6, o6, e7, o7, e8, o8, e9, o9);
#undef PSTEP
    }

    size_t ob = (size_t)bc * 2401 + (size_t)py * 49 + px0;
    out1[ob] = a10; out2[ob] = a20;
    if (px0 < 48) {
        out1[ob + 1] = a11; out1[ob + 2] = a12; out1[ob + 3] = a13;
        out1[ob + 4] = a14; out1[ob + 5] = a15; out1[ob + 6] = a16; out1[ob + 7] = a17;
        out2[ob + 1] = a21; out2[ob + 2] = a22; out2[ob + 3] = a23;
        out2[ob + 4] = a24; out2[ob + 5] = a25; out2[ob + 6] = a26; out2[ob + 7] = a27;
    }
}

extern "C" void kernel_launch(void* const* d_in, const int* in_sizes, int n_in,
                              void* d_out, int out_size, void* d_ws, size_t ws_size,
                              hipStream_t stream) {
    const float* img = (const float*)d_in[0];
    const float* t1  = (const float*)d_in[1];
    const float* t2  = (const float*)d_in[2];
    const float* w1  = (const float*)d_in[3];
    const float* b1  = (const float*)d_in[4];
    const float* w2  = (const float*)d_in[5];
    const float* b2  = (const float*)d_in[6];
    float* out = (float*)d_out;

    char* ws = (char*)d_ws;
    __hip_bfloat16* bufA = (__hip_bfloat16*)ws;                 // 66,064,384 B
    __hip_bfloat16* w1t  = (__hip_bfloat16*)(ws + 66064384);    // 4,096 B
    __hip_bfloat16* w2k  = (__hip_bfloat16*)(ws + 66068480);    // 147,456 B
    __half* xf = (__half*)(ws + 66215936);                      // 31,490,048
    __half* k1 = (__half*)(ws + 97705984);                      // 1,605,632
    __half* k2 = (__half*)(ws + 99311616);                      // end 100,917,248

    wt_xform_all<<<296, 256, 0, stream>>>(w1, w2, w1t, w2k);

    conv1_mfma<<<dim3(256, 1, 32), 256, 0, stream>>>(img, w1t, b1, bufA,
                                                     256, 256, 127, 127, 16);
    conv2_mfma<<<dim3(128, 1, 32), 256, 0, stream>>>(bufA, w2k, b2, xf,
                                                     127, 127, 62, 62, 8);

    conv1_mfma<<<dim3(16, 1, 32), 256, 0, stream>>>(t1, w1t, b1, bufA,
                                                    64, 64, 31, 31, 4);
    conv2_mfma<<<dim3(8, 1, 32), 256, 0, stream>>>(bufA, w2k, b2, k1,
                                                   31, 31, 14, 14, 2);
    conv1_mfma<<<dim3(16, 1, 32), 256, 0, stream>>>(t2, w1t, b1, bufA,
                                                    64, 64, 31, 31, 4);
    conv2_mfma<<<dim3(8, 1, 32), 256, 0, stream>>>(bufA, w2k, b2, k2,
                                                   31, 31, 14, 14, 2);

    xcorr_dual<<<4096, 384, 0, stream>>>(xf, k1, k2, out, out + (size_t)9834496);
}

// Round 8
// 281.034 us; speedup vs baseline: 33.0194x; 1.1890x over previous
//
#include <hip/hip_runtime.h>
#include <hip/hip_bf16.h>
#include <hip/hip_fp16.h>

typedef __attribute__((ext_vector_type(8))) short bf16x8;
typedef __attribute__((ext_vector_type(4))) float f32x4;
typedef __attribute__((ext_vector_type(2))) _Float16 f16x2;

__device__ __forceinline__ float dot2f16(unsigned a, unsigned b, float c) {
#if __has_builtin(__builtin_amdgcn_fdot2)
    return __builtin_amdgcn_fdot2(__builtin_bit_cast(f16x2, a),
                                  __builtin_bit_cast(f16x2, b), c, false);
#else
    union { unsigned u; __half2 h; } ua, ub;
    ua.u = a; ub.u = b;
    return c + __low2float(ua.h) * __low2float(ub.h)
             + __high2float(ua.h) * __high2float(ub.h);
#endif
}

// ---------------- weight transforms -------------------------------------------
// w1 [64][3][3][3] f32 -> w1t [64][32] bf16 (k = ic*9+ky*3+kx, pad 27..31 = 0)
// w2 [128][64][3][3] f32 -> w2h [9][2][4][128][8] bf16: per (kk,h) an 8KB panel,
//   slot-major [c][oc][e] (ic = h*32 + c*8 + e) -> linear staging + conflict-free reads.
__global__ void wt_xform_all(const float* __restrict__ w1, const float* __restrict__ w2,
                             __hip_bfloat16* __restrict__ w1t, __hip_bfloat16* __restrict__ w2h) {
    int i = blockIdx.x * 256 + threadIdx.x;
    if (i < 2048) {
        int oc = i >> 5, k = i & 31;
        w1t[i] = (k < 27) ? __float2bfloat16(w1[oc * 27 + k]) : __float2bfloat16(0.f);
        return;
    }
    int j = i - 2048;
    if (j < 9 * 2 * 4 * 128 * 8) {
        int e  = j & 7;
        int oc = (j >> 3) & 127;
        int c  = (j >> 10) & 3;
        int h  = (j >> 12) & 1;
        int kk = j >> 13;
        int ic = h * 32 + c * 8 + e;
        int ky = kk / 3, kx = kk - ky * 3;
        w2h[j] = __float2bfloat16(w2[(((size_t)oc * 64 + ic) * 3 + ky) * 3 + kx]);
    }
}

// ---------------- conv1 implicit-GEMM on MFMA + fused bias/relu/maxpool ---------
__global__ void __launch_bounds__(256, 2)
conv1_mfma(const float* __restrict__ in,
           const __hip_bfloat16* __restrict__ w1t,
           const float* __restrict__ bias,
           __hip_bfloat16* __restrict__ out,
           int Hin, int Win, int PH, int PW, int tilesX) {
    __shared__ unsigned short xs[3 * 324];   // [ic][18 rows][18 cols] bf16 bits
    int t = threadIdx.x;
    int tile = blockIdx.x;
    int tileY = tile / tilesX, tileX = tile - tileY * tilesX;
    int b = blockIdx.z;
    int y0 = tileY * 16, x0 = tileX * 16;

    const float* inb = in + (size_t)b * 3 * Hin * Win;
    for (int i = t; i < 972; i += 256) {
        int ic = i / 324, rem = i - ic * 324;
        int r = rem / 18, c = rem - r * 18;
        int gy = y0 + r, gx = x0 + c;
        float v = 0.f;
        if (gy < Hin && gx < Win) v = inb[((size_t)ic * Hin + gy) * Win + gx];
        __hip_bfloat16 hv = __float2bfloat16(v);
        xs[i] = *(unsigned short*)&hv;
    }
    __syncthreads();

    int lane = t & 63, wv = t >> 6;
    int l15 = lane & 15, l4 = lane >> 4;

    bf16x8 af[4];
#pragma unroll
    for (int m = 0; m < 4; ++m)
        af[m] = *(const bf16x8*)&w1t[((size_t)(m * 16 + l15)) * 32 + l4 * 8];

    int off0, off1, off2, off3, off4, off5, off6, off7;
    int ok0, ok1, ok2, ok3, ok4, ok5, ok6, ok7;
#define MKOFF(J) { int kk = l4 * 8 + J; int ic = kk / 9; int r9 = kk - ic * 9; \
                   int ky = r9 / 3; int kx = r9 - ky * 3; \
                   ok##J = (kk < 27); off##J = ok##J ? (ic * 324 + ky * 18 + kx) : 0; }
    MKOFF(0) MKOFF(1) MKOFF(2) MKOFF(3) MKOFF(4) MKOFF(5) MKOFF(6) MKOFF(7)
#undef MKOFF

    f32x4 acc[4][4];
#pragma unroll
    for (int m = 0; m < 4; ++m)
#pragma unroll
        for (int n = 0; n < 4; ++n) acc[m][n] = (f32x4)(0.f);

#pragma unroll
    for (int n = 0; n < 4; ++n) {
        int y = wv * 4 + n;
        int base = y * 18 + l15;
        bf16x8 bfr;
        bfr[0] = ok0 ? (short)xs[base + off0] : (short)0;
        bfr[1] = ok1 ? (short)xs[base + off1] : (short)0;
        bfr[2] = ok2 ? (short)xs[base + off2] : (short)0;
        bfr[3] = ok3 ? (short)xs[base + off3] : (short)0;
        bfr[4] = ok4 ? (short)xs[base + off4] : (short)0;
        bfr[5] = ok5 ? (short)xs[base + off5] : (short)0;
        bfr[6] = ok6 ? (short)xs[base + off6] : (short)0;
        bfr[7] = ok7 ? (short)xs[base + off7] : (short)0;
#pragma unroll
        for (int m = 0; m < 4; ++m)
            acc[m][n] = __builtin_amdgcn_mfma_f32_16x16x32_bf16(af[m], bfr, acc[m][n], 0, 0, 0);
    }

    int qx = tileX * 8 + (l15 >> 1);
    bool xok = ((lane & 1) == 0) && (qx < PW);
#pragma unroll
    for (int m = 0; m < 4; ++m) {
        int ocb = m * 16 + l4 * 4;
#pragma unroll
        for (int np = 0; np < 2; ++np) {
            int qy = tileY * 8 + wv * 2 + np;
            union { __hip_bfloat16 h[4]; uint2 v; } pk;
#pragma unroll
            for (int r = 0; r < 4; ++r) {
                float v = fmaxf(acc[m][2 * np][r], acc[m][2 * np + 1][r]);
                v = fmaxf(v, __shfl_xor(v, 1));
                pk.h[r] = __float2bfloat16(fmaxf(v + bias[ocb + r], 0.f));
            }
            if (xok && qy < PH)
                *(uint2*)&out[(((size_t)b * PH + qy) * PW + qx) * 64 + ocb] = pk.v;
        }
    }
}

// ---------------- conv2 implicit-GEMM: 18-phase ic-half A-dbuf, 4 blocks/CU ------
// w2h panels [9][2][4 slot][128 oc][8] bf16 (8KB each). Per phase (kk,h):
// linear reg-prefetch next panel, 4 A + 4 B ds_reads, 16 MFMA, ds_write, barrier.
// LDS 39.4KB -> 4 blocks/CU (16 waves) vs R7's 55.8KB/2 blocks: latency-bound fix.
// Tile index bx = tileX*tilesY + tileY so same-row writers share an XCD L2.
__global__ void __launch_bounds__(256, 4)
conv2_mfma(const __hip_bfloat16* __restrict__ xin,
           const __hip_bfloat16* __restrict__ w2h,
           const float* __restrict__ bias, __half* __restrict__ out,
           int H1, int W1, int PH, int PW, int tilesY) {
    __shared__ uint4 xl4[10 * 18 * 8];   // 23040 B input tile; reused as store buffer
    __shared__ uint4 aw[2][512];         // 2 x 8 KB weight half-panels

    int t = threadIdx.x;
    int tile = blockIdx.x;
    int tileY = tile % tilesY, tileX = tile / tilesY;
    int b = blockIdx.z;
    int y0 = tileY * 8, x0 = tileX * 16;

    const __hip_bfloat16* xb = xin + (size_t)b * H1 * W1 * 64;
    for (int s = t; s < 1440; s += 256) {
        int pixel = s >> 3, si = s & 7;
        int row = pixel / 18, col = pixel - row * 18;
        int gy = y0 + row, gx = x0 + col;
        uint4 v = make_uint4(0, 0, 0, 0);
        if (gy < H1 && gx < W1)
            v = *(const uint4*)&xb[((size_t)gy * W1 + gx) * 64 + si * 8];
        xl4[(pixel << 3) | (si ^ (col & 7))] = v;
    }
    // stage panel (kk=0,h=0): linear copy
    {
        const uint4* src = (const uint4*)w2h;
        aw[0][t] = src[t];
        aw[0][t + 256] = src[t + 256];
    }
    __syncthreads();

    int lane = t & 63;
    int wid = t >> 6;
    int wr = wid >> 1;
    int wc = wid & 1;
    int l15 = lane & 15, l4 = lane >> 4;

    f32x4 acc[4][4];
#pragma unroll
    for (int m = 0; m < 4; ++m)
#pragma unroll
        for (int n = 0; n < 4; ++n) acc[m][n] = (f32x4)(0.f);

    for (int p = 0; p < 18; ++p) {
        const int cur = p & 1;
        const int kk = p >> 1, h = p & 1;

        // prefetch next half-panel into regs (linear, coalesced)
        uint4 pf0, pf1;
        if (p < 17) {
            const uint4* src = (const uint4*)w2h + (size_t)(p + 1) * 512;
            pf0 = src[t];
            pf1 = src[t + 256];
        }

        const int ky = kk / 3, kx = kk - ky * 3;
        const int col = l15 + kx;
        const int sidx = (h * 4 + l4) ^ (col & 7);

        bf16x8 af[4], bfv[4];
#pragma unroll
        for (int m = 0; m < 4; ++m) {
            int oc = wr * 64 + m * 16 + l15;
            af[m] = *(const bf16x8*)&aw[cur][l4 * 128 + oc];
        }
#pragma unroll
        for (int n = 0; n < 4; ++n) {
            int row = wc * 4 + n + ky;
            bfv[n] = *(const bf16x8*)&xl4[((row * 18 + col) << 3) | sidx];
        }
#pragma unroll
        for (int m = 0; m < 4; ++m)
#pragma unroll
            for (int n = 0; n < 4; ++n)
                acc[m][n] = __builtin_amdgcn_mfma_f32_16x16x32_bf16(
                    af[m], bfv[n], acc[m][n], 0, 0, 0);

        if (p < 17) {
            aw[cur ^ 1][t] = pf0;
            aw[cur ^ 1][t + 256] = pf1;
        }
        __syncthreads();
    }

    // epilogue: pool + bias + relu -> LDS f16 -> contiguous NCHW stores
    __half* plds = (__half*)xl4;
#pragma unroll
    for (int m = 0; m < 4; ++m) {
        int ocb = wr * 64 + m * 16 + l4 * 4;
#pragma unroll
        for (int np = 0; np < 2; ++np) {
            int qyl = wc * 2 + np;
#pragma unroll
            for (int r = 0; r < 4; ++r) {
                float v = fmaxf(acc[m][2 * np][r], acc[m][2 * np + 1][r]);
                v = fmaxf(v, __shfl_xor(v, 1));
                if ((lane & 1) == 0) {
                    float u = fmaxf(v + bias[ocb + r], 0.f);
                    plds[((ocb + r) * 4 + qyl) * 8 + (l15 >> 1)] = __float2half(u);
                }
            }
        }
    }
    __syncthreads();

    int qx0 = tileX * 8, qy0 = tileY * 4;
    for (int i = t; i < 512; i += 256) {
        int oc = i >> 2, qy = i & 3;
        int gqy = qy0 + qy;
        if (gqy < PH) {
            __half* dst = out + (((size_t)b * 128 + oc) * PH + gqy) * PW + qx0;
            const __half* src = &plds[i * 8];
            if (qx0 + 8 <= PW) {
                *(uint4*)dst = *(const uint4*)src;
            } else {
                for (int q = 0; q < 8 && qx0 + q < PW; ++q) dst[q] = src[q];
            }
        }
    }
}

// ---------------- fused dual depthwise xcorr, packed f16 dot2 --------------------
__global__ void xcorr_dual(const __half* __restrict__ x, const __half* __restrict__ k1,
                           const __half* __restrict__ k2,
                           float* __restrict__ out1, float* __restrict__ out2) {
    __shared__ __half xl[62 * 66 + 8];
    __shared__ unsigned kl[224];
    int bc = blockIdx.x;
    int t = threadIdx.x;

    const unsigned* xp = (const unsigned*)(x + (size_t)bc * 3844);
    unsigned* xld = (unsigned*)xl;
    for (int d = t; d < 1922; d += 384) {
        int r = d / 31, c2 = d - r * 31;
        xld[r * 33 + c2] = xp[d];
    }
    if (t < 98) {
        int ky = t / 7, p = t - ky * 7;
        kl[ky * 8 + p] = ((const unsigned*)(k1 + (size_t)bc * 196))[t];
    } else if (t < 196) {
        int i = t - 98;
        int ky = i / 7, p = i - ky * 7;
        kl[112 + ky * 8 + p] = ((const unsigned*)(k2 + (size_t)bc * 196))[i];
    }
    __syncthreads();

    if (t >= 343) return;
    int py = t % 49;
    int px0 = (t / 49) * 8;

    float a10 = 0.f, a11 = 0.f, a12 = 0.f, a13 = 0.f;
    float a14 = 0.f, a15 = 0.f, a16 = 0.f, a17 = 0.f;
    float a20 = 0.f, a21 = 0.f, a22 = 0.f, a23 = 0.f;
    float a24 = 0.f, a25 = 0.f, a26 = 0.f, a27 = 0.f;

    for (int ky = 0; ky < 14; ++ky) {
        const unsigned* row = (const unsigned*)&xl[(py + ky) * 66 + px0];
        unsigned e0 = row[0], e1 = row[1], e2 = row[2], e3 = row[3], e4 = row[4];
        unsigned e5 = row[5], e6 = row[6], e7 = row[7], e8 = row[8], e9 = row[9];
        unsigned e10 = row[10];
        unsigned o0 = (e0 >> 16) | (e1 << 16);
        unsigned o1 = (e1 >> 16) | (e2 << 16);
        unsigned o2 = (e2 >> 16) | (e3 << 16);
        unsigned o3 = (e3 >> 16) | (e4 << 16);
        unsigned o4 = (e4 >> 16) | (e5 << 16);
        unsigned o5 = (e5 >> 16) | (e6 << 16);
        unsigned o6 = (e6 >> 16) | (e7 << 16);
        unsigned o7 = (e7 >> 16) | (e8 << 16);
        unsigned o8 = (e8 >> 16) | (e9 << 16);
        unsigned o9 = (e9 >> 16) | (e10 << 16);
        int kb = ky * 8;
#define PSTEP(P, EA, OA, EB, OB, EC, OC, ED, OD) do { \
        unsigned kp1 = kl[kb + (P)]; unsigned kp2 = kl[kb + 112 + (P)]; \
        a10 = dot2f16(kp1, EA, a10); a20 = dot2f16(kp2, EA, a20); \
        a11 = dot2f16(kp1, OA, a11); a21 = dot2f16(kp2, OA, a21); \
        a12 = dot2f16(kp1, EB, a12); a22 = dot2f16(kp2, EB, a22); \
        a13 = dot2f16(kp1, OB, a13); a23 = dot2f16(kp2, OB, a23); \
        a14 = dot2f16(kp1, EC, a14); a24 = dot2f16(kp2, EC, a24); \
        a15 = dot2f16(kp1, OC, a15); a25 = dot2f16(kp2, OC, a25); \
        a16 = dot2f16(kp1, ED, a16); a26 = dot2f16(kp2, ED, a26); \
        a17 = dot2f16(kp1, OD, a17); a27 = dot2f16(kp2, OD, a27); \
        } while (0)
        PSTEP(0, e0, o0, e1, o1, e2, o2, e3, o3);
        PSTEP(1, e1, o1, e2, o2, e3, o3, e4, o4);
        PSTEP(2, e2, o2, e3, o3, e4, o4, e5, o5);
        PSTEP(3, e3, o3, e4, o4, e5, o5, e6, o6);
        PSTEP(4, e4, o4, e5, o5, e6, o6, e7, o7);
        PSTEP(5, e5, o5, e6, o6, e7, o7, e8, o8);
        PSTEP(6, e6, o6, e7, o7, e8, o8, e9, o9);
#undef PSTEP
    }

    size_t ob = (size_t)bc * 2401 + (size_t)py * 49 + px0;
    out1[ob] = a10; out2[ob] = a20;
    if (px0 < 48) {
        out1[ob + 1] = a11; out1[ob + 2] = a12; out1[ob + 3] = a13;
        out1[ob + 4] = a14; out1[ob + 5] = a15; out1[ob + 6] = a16; out1[ob + 7] = a17;
        out2[ob + 1] = a21; out2[ob + 2] = a22; out2[ob + 3] = a23;
        out2[ob + 4] = a24; out2[ob + 5] = a25; out2[ob + 6] = a26; out2[ob + 7] = a27;
    }
}

extern "C" void kernel_launch(void* const* d_in, const int* in_sizes, int n_in,
                              void* d_out, int out_size, void* d_ws, size_t ws_size,
                              hipStream_t stream) {
    const float* img = (const float*)d_in[0];
    const float* t1  = (const float*)d_in[1];
    const float* t2  = (const float*)d_in[2];
    const float* w1  = (const float*)d_in[3];
    const float* b1  = (const float*)d_in[4];
    const float* w2  = (const float*)d_in[5];
    const float* b2  = (const float*)d_in[6];
    float* out = (float*)d_out;

    char* ws = (char*)d_ws;
    __hip_bfloat16* bufA = (__hip_bfloat16*)ws;                 // 66,064,384 B
    __hip_bfloat16* w1t  = (__hip_bfloat16*)(ws + 66064384);    // 4,096 B
    __hip_bfloat16* w2h  = (__hip_bfloat16*)(ws + 66068480);    // 147,456 B
    __half* xf = (__half*)(ws + 66215936);                      // 31,490,048
    __half* k1 = (__half*)(ws + 97705984);                      // 1,605,632
    __half* k2 = (__half*)(ws + 99311616);                      // end 100,917,248

    wt_xform_all<<<296, 256, 0, stream>>>(w1, w2, w1t, w2h);

    conv1_mfma<<<dim3(256, 1, 32), 256, 0, stream>>>(img, w1t, b1, bufA,
                                                     256, 256, 127, 127, 16);
    // image conv2: tilesX=8, tilesY=16 -> grid.x = 128, bx = tileX*16 + tileY
    conv2_mfma<<<dim3(128, 1, 32), 256, 0, stream>>>(bufA, w2h, b2, xf,
                                                     127, 127, 62, 62, 16);

    conv1_mfma<<<dim3(16, 1, 32), 256, 0, stream>>>(t1, w1t, b1, bufA,
                                                    64, 64, 31, 31, 4);
    conv2_mfma<<<dim3(8, 1, 32), 256, 0, stream>>>(bufA, w2h, b2, k1,
                                                   31, 31, 14, 14, 4);
    conv1_mfma<<<dim3(16, 1, 32), 256, 0, stream>>>(t2, w1t, b1, bufA,
                                                    64, 64, 31, 31, 4);
    conv2_mfma<<<dim3(8, 1, 32), 256, 0, stream>>>(bufA, w2h, b2, k2,
                                                   31, 31, 14, 14, 4);

    xcorr_dual<<<4096, 384, 0, stream>>>(xf, k1, k2, out, out + (size_t)9834496);
}

// Round 9
// 278.980 us; speedup vs baseline: 33.2625x; 1.0074x over previous
//
#include <hip/hip_runtime.h>
#include <hip/hip_bf16.h>
#include <hip/hip_fp16.h>

typedef __attribute__((ext_vector_type(8))) short bf16x8;
typedef __attribute__((ext_vector_type(4))) float f32x4;
typedef __attribute__((ext_vector_type(2))) _Float16 f16x2;

__device__ __forceinline__ float dot2f16(unsigned a, unsigned b, float c) {
#if __has_builtin(__builtin_amdgcn_fdot2)
    return __builtin_amdgcn_fdot2(__builtin_bit_cast(f16x2, a),
                                  __builtin_bit_cast(f16x2, b), c, false);
#else
    union { unsigned u; __half2 h; } ua, ub;
    ua.u = a; ub.u = b;
    return c + __low2float(ua.h) * __low2float(ub.h)
             + __high2float(ua.h) * __high2float(ub.h);
#endif
}

// ---------------- weight transforms -------------------------------------------
// w1 [64][3][3][3] f32 -> w1t [64][32] bf16 (k = ic*9+ky*3+kx, pad 27..31 = 0)
// w2 [128][64][3][3] f32 -> w2h [9][2][4][128][8] bf16 panels
__global__ void wt_xform_all(const float* __restrict__ w1, const float* __restrict__ w2,
                             __hip_bfloat16* __restrict__ w1t, __hip_bfloat16* __restrict__ w2h) {
    int i = blockIdx.x * 256 + threadIdx.x;
    if (i < 2048) {
        int oc = i >> 5, k = i & 31;
        w1t[i] = (k < 27) ? __float2bfloat16(w1[oc * 27 + k]) : __float2bfloat16(0.f);
        return;
    }
    int j = i - 2048;
    if (j < 9 * 2 * 4 * 128 * 8) {
        int e  = j & 7;
        int oc = (j >> 3) & 127;
        int c  = (j >> 10) & 3;
        int h  = (j >> 12) & 1;
        int kk = j >> 13;
        int ic = h * 32 + c * 8 + e;
        int ky = kk / 3, kx = kk - ky * 3;
        w2h[j] = __float2bfloat16(w2[(((size_t)oc * 64 + ic) * 3 + ky) * 3 + kx]);
    }
}

// ---------------- conv1 implicit-GEMM on MFMA + fused bias/relu/maxpool ---------
__global__ void __launch_bounds__(256, 2)
conv1_mfma(const float* __restrict__ in,
           const __hip_bfloat16* __restrict__ w1t,
           const float* __restrict__ bias,
           __hip_bfloat16* __restrict__ out,
           int Hin, int Win, int PH, int PW, int tilesX) {
    __shared__ unsigned short xs[3 * 324];   // [ic][18 rows][18 cols] bf16 bits
    int t = threadIdx.x;
    int tile = blockIdx.x;
    int tileY = tile / tilesX, tileX = tile - tileY * tilesX;
    int b = blockIdx.z;
    int y0 = tileY * 16, x0 = tileX * 16;

    const float* inb = in + (size_t)b * 3 * Hin * Win;
    for (int i = t; i < 972; i += 256) {
        int ic = i / 324, rem = i - ic * 324;
        int r = rem / 18, c = rem - r * 18;
        int gy = y0 + r, gx = x0 + c;
        float v = 0.f;
        if (gy < Hin && gx < Win) v = inb[((size_t)ic * Hin + gy) * Win + gx];
        __hip_bfloat16 hv = __float2bfloat16(v);
        xs[i] = *(unsigned short*)&hv;
    }
    __syncthreads();

    int lane = t & 63, wv = t >> 6;
    int l15 = lane & 15, l4 = lane >> 4;

    bf16x8 af[4];
#pragma unroll
    for (int m = 0; m < 4; ++m)
        af[m] = *(const bf16x8*)&w1t[((size_t)(m * 16 + l15)) * 32 + l4 * 8];

    int off0, off1, off2, off3, off4, off5, off6, off7;
    int ok0, ok1, ok2, ok3, ok4, ok5, ok6, ok7;
#define MKOFF(J) { int kk = l4 * 8 + J; int ic = kk / 9; int r9 = kk - ic * 9; \
                   int ky = r9 / 3; int kx = r9 - ky * 3; \
                   ok##J = (kk < 27); off##J = ok##J ? (ic * 324 + ky * 18 + kx) : 0; }
    MKOFF(0) MKOFF(1) MKOFF(2) MKOFF(3) MKOFF(4) MKOFF(5) MKOFF(6) MKOFF(7)
#undef MKOFF

    f32x4 acc[4][4];
#pragma unroll
    for (int m = 0; m < 4; ++m)
#pragma unroll
        for (int n = 0; n < 4; ++n) acc[m][n] = (f32x4)(0.f);

#pragma unroll
    for (int n = 0; n < 4; ++n) {
        int y = wv * 4 + n;
        int base = y * 18 + l15;
        bf16x8 bfr;
        bfr[0] = ok0 ? (short)xs[base + off0] : (short)0;
        bfr[1] = ok1 ? (short)xs[base + off1] : (short)0;
        bfr[2] = ok2 ? (short)xs[base + off2] : (short)0;
        bfr[3] = ok3 ? (short)xs[base + off3] : (short)0;
        bfr[4] = ok4 ? (short)xs[base + off4] : (short)0;
        bfr[5] = ok5 ? (short)xs[base + off5] : (short)0;
        bfr[6] = ok6 ? (short)xs[base + off6] : (short)0;
        bfr[7] = ok7 ? (short)xs[base + off7] : (short)0;
#pragma unroll
        for (int m = 0; m < 4; ++m)
            acc[m][n] = __builtin_amdgcn_mfma_f32_16x16x32_bf16(af[m], bfr, acc[m][n], 0, 0, 0);
    }

    int qx = tileX * 8 + (l15 >> 1);
    bool xok = ((lane & 1) == 0) && (qx < PW);
#pragma unroll
    for (int m = 0; m < 4; ++m) {
        int ocb = m * 16 + l4 * 4;
#pragma unroll
        for (int np = 0; np < 2; ++np) {
            int qy = tileY * 8 + wv * 2 + np;
            union { __hip_bfloat16 h[4]; uint2 v; } pk;
#pragma unroll
            for (int r = 0; r < 4; ++r) {
                float v = fmaxf(acc[m][2 * np][r], acc[m][2 * np + 1][r]);
                v = fmaxf(v, __shfl_xor(v, 1));
                pk.h[r] = __float2bfloat16(fmaxf(v + bias[ocb + r], 0.f));
            }
            if (xok && qy < PH)
                *(uint2*)&out[(((size_t)b * PH + qy) * PW + qx) * 64 + ocb] = pk.v;
        }
    }
}

// ---------------- conv2 implicit-GEMM: 18-phase ic-half A-dbuf, 4 blocks/CU ------
__global__ void __launch_bounds__(256, 4)
conv2_mfma(const __hip_bfloat16* __restrict__ xin,
           const __hip_bfloat16* __restrict__ w2h,
           const float* __restrict__ bias, __half* __restrict__ out,
           int H1, int W1, int PH, int PW, int tilesY) {
    __shared__ uint4 xl4[10 * 18 * 8];   // 23040 B input tile; reused as store buffer
    __shared__ uint4 aw[2][512];         // 2 x 8 KB weight half-panels

    int t = threadIdx.x;
    int tile = blockIdx.x;
    int tileY = tile % tilesY, tileX = tile / tilesY;
    int b = blockIdx.z;
    int y0 = tileY * 8, x0 = tileX * 16;

    const __hip_bfloat16* xb = xin + (size_t)b * H1 * W1 * 64;
    for (int s = t; s < 1440; s += 256) {
        int pixel = s >> 3, si = s & 7;
        int row = pixel / 18, col = pixel - row * 18;
        int gy = y0 + row, gx = x0 + col;
        uint4 v = make_uint4(0, 0, 0, 0);
        if (gy < H1 && gx < W1)
            v = *(const uint4*)&xb[((size_t)gy * W1 + gx) * 64 + si * 8];
        xl4[(pixel << 3) | (si ^ (col & 7))] = v;
    }
    {
        const uint4* src = (const uint4*)w2h;
        aw[0][t] = src[t];
        aw[0][t + 256] = src[t + 256];
    }
    __syncthreads();

    int lane = t & 63;
    int wid = t >> 6;
    int wr = wid >> 1;
    int wc = wid & 1;
    int l15 = lane & 15, l4 = lane >> 4;

    f32x4 acc[4][4];
#pragma unroll
    for (int m = 0; m < 4; ++m)
#pragma unroll
        for (int n = 0; n < 4; ++n) acc[m][n] = (f32x4)(0.f);

    for (int p = 0; p < 18; ++p) {
        const int cur = p & 1;
        const int kk = p >> 1, h = p & 1;

        uint4 pf0, pf1;
        if (p < 17) {
            const uint4* src = (const uint4*)w2h + (size_t)(p + 1) * 512;
            pf0 = src[t];
            pf1 = src[t + 256];
        }

        const int ky = kk / 3, kx = kk - ky * 3;
        const int col = l15 + kx;
        const int sidx = (h * 4 + l4) ^ (col & 7);

        bf16x8 af[4], bfv[4];
#pragma unroll
        for (int m = 0; m < 4; ++m) {
            int oc = wr * 64 + m * 16 + l15;
            af[m] = *(const bf16x8*)&aw[cur][l4 * 128 + oc];
        }
#pragma unroll
        for (int n = 0; n < 4; ++n) {
            int row = wc * 4 + n + ky;
            bfv[n] = *(const bf16x8*)&xl4[((row * 18 + col) << 3) | sidx];
        }
#pragma unroll
        for (int m = 0; m < 4; ++m)
#pragma unroll
            for (int n = 0; n < 4; ++n)
                acc[m][n] = __builtin_amdgcn_mfma_f32_16x16x32_bf16(
                    af[m], bfv[n], acc[m][n], 0, 0, 0);

        if (p < 17) {
            aw[cur ^ 1][t] = pf0;
            aw[cur ^ 1][t + 256] = pf1;
        }
        __syncthreads();
    }

    __half* plds = (__half*)xl4;
#pragma unroll
    for (int m = 0; m < 4; ++m) {
        int ocb = wr * 64 + m * 16 + l4 * 4;
#pragma unroll
        for (int np = 0; np < 2; ++np) {
            int qyl = wc * 2 + np;
#pragma unroll
            for (int r = 0; r < 4; ++r) {
                float v = fmaxf(acc[m][2 * np][r], acc[m][2 * np + 1][r]);
                v = fmaxf(v, __shfl_xor(v, 1));
                if ((lane & 1) == 0) {
                    float u = fmaxf(v + bias[ocb + r], 0.f);
                    plds[((ocb + r) * 4 + qyl) * 8 + (l15 >> 1)] = __float2half(u);
                }
            }
        }
    }
    __syncthreads();

    int qx0 = tileX * 8, qy0 = tileY * 4;
    for (int i = t; i < 512; i += 256) {
        int oc = i >> 2, qy = i & 3;
        int gqy = qy0 + qy;
        if (gqy < PH) {
            __half* dst = out + (((size_t)b * 128 + oc) * PH + gqy) * PW + qx0;
            const __half* src = &plds[i * 8];
            if (qx0 + 8 <= PW) {
                *(uint4*)dst = *(const uint4*)src;
            } else {
                for (int q = 0; q < 8 && qx0 + q < PW; ++q) dst[q] = src[q];
            }
        }
    }
}

// ---------------- fused dual depthwise xcorr -------------------------------------
// x plane in LDS; kernel pairs read DIRECTLY from global with block-uniform
// indices -> hipcc emits s_load (scalar cache, off the LDS pipe). R8 showed the
// 14 uniform kl LDS reads/ky were the LDS-pipe bottleneck (~70us of 108).
__global__ void xcorr_dual(const __half* __restrict__ x, const __half* __restrict__ k1,
                           const __half* __restrict__ k2,
                           float* __restrict__ out1, float* __restrict__ out2) {
    __shared__ __half xl[62 * 66 + 8];
    int bc = blockIdx.x;
    int t = threadIdx.x;

    const unsigned* xp = (const unsigned*)(x + (size_t)bc * 3844);
    unsigned* xld = (unsigned*)xl;
    for (int d = t; d < 1922; d += 384) {
        int r = d / 31, c2 = d - r * 31;
        xld[r * 33 + c2] = xp[d];
    }
    // uniform (scalar) kernel row base pointers
    const unsigned* kg1 = (const unsigned*)(k1 + (size_t)bc * 196);
    const unsigned* kg2 = (const unsigned*)(k2 + (size_t)bc * 196);
    __syncthreads();

    if (t >= 343) return;
    int py = t % 49;
    int px0 = (t / 49) * 8;

    float a10 = 0.f, a11 = 0.f, a12 = 0.f, a13 = 0.f;
    float a14 = 0.f, a15 = 0.f, a16 = 0.f, a17 = 0.f;
    float a20 = 0.f, a21 = 0.f, a22 = 0.f, a23 = 0.f;
    float a24 = 0.f, a25 = 0.f, a26 = 0.f, a27 = 0.f;

    for (int ky = 0; ky < 14; ++ky) {
        const unsigned* row = (const unsigned*)&xl[(py + ky) * 66 + px0];
        unsigned e0 = row[0], e1 = row[1], e2 = row[2], e3 = row[3], e4 = row[4];
        unsigned e5 = row[5], e6 = row[6], e7 = row[7], e8 = row[8], e9 = row[9];
        unsigned e10 = row[10];
        unsigned o0 = (e0 >> 16) | (e1 << 16);
        unsigned o1 = (e1 >> 16) | (e2 << 16);
        unsigned o2 = (e2 >> 16) | (e3 << 16);
        unsigned o3 = (e3 >> 16) | (e4 << 16);
        unsigned o4 = (e4 >> 16) | (e5 << 16);
        unsigned o5 = (e5 >> 16) | (e6 << 16);
        unsigned o6 = (e6 >> 16) | (e7 << 16);
        unsigned o7 = (e7 >> 16) | (e8 << 16);
        unsigned o8 = (e8 >> 16) | (e9 << 16);
        unsigned o9 = (e9 >> 16) | (e10 << 16);
        const unsigned* kr1 = kg1 + ky * 7;   // uniform -> s_load
        const unsigned* kr2 = kg2 + ky * 7;
#define PSTEP(P, EA, OA, EB, OB, EC, OC, ED, OD) do { \
        unsigned kp1 = kr1[P]; unsigned kp2 = kr2[P]; \
        a10 = dot2f16(kp1, EA, a10); a20 = dot2f16(kp2, EA, a20); \
        a11 = dot2f16(kp1, OA, a11); a21 = dot2f16(kp2, OA, a21); \
        a12 = dot2f16(kp1, EB, a12); a22 = dot2f16(kp2, EB, a22); \
        a13 = dot2f16(kp1, OB, a13); a23 = dot2f16(kp2, OB, a23); \
        a14 = dot2f16(kp1, EC, a14); a24 = dot2f16(kp2, EC, a24); \
        a15 = dot2f16(kp1, OC, a15); a25 = dot2f16(kp2, OC, a25); \
        a16 = dot2f16(kp1, ED, a16); a26 = dot2f16(kp2, ED, a26); \
        a17 = dot2f16(kp1, OD, a17); a27 = dot2f16(kp2, OD, a27); \
        } while (0)
        PSTEP(0, e0, o0, e1, o1, e2, o2, e3, o3);
        PSTEP(1, e1, o1, e2, o2, e3, o3, e4, o4);
        PSTEP(2, e2, o2, e3, o3, e4, o4, e5, o5);
        PSTEP(3, e3, o3, e4, o4, e5, o5, e6, o6);
        PSTEP(4, e4, o4, e5, o5, e6, o6, e7, o7);
        PSTEP(5, e5, o5, e6, o6, e7, o7, e8, o8);
        PSTEP(6, e6, o6, e7, o7, e8, o8, e9, o9);
#undef PSTEP
    }

    size_t ob = (size_t)bc * 2401 + (size_t)py * 49 + px0;
    out1[ob] = a10; out2[ob] = a20;
    if (px0 < 48) {
        out1[ob + 1] = a11; out1[ob + 2] = a12; out1[ob + 3] = a13;
        out1[ob + 4] = a14; out1[ob + 5] = a15; out1[ob + 6] = a16; out1[ob + 7] = a17;
        out2[ob + 1] = a21; out2[ob + 2] = a22; out2[ob + 3] = a23;
        out2[ob + 4] = a24; out2[ob + 5] = a25; out2[ob + 6] = a26; out2[ob + 7] = a27;
    }
}

extern "C" void kernel_launch(void* const* d_in, const int* in_sizes, int n_in,
                              void* d_out, int out_size, void* d_ws, size_t ws_size,
                              hipStream_t stream) {
    const float* img = (const float*)d_in[0];
    const float* t1  = (const float*)d_in[1];
    const float* t2  = (const float*)d_in[2];
    const float* w1  = (const float*)d_in[3];
    const float* b1  = (const float*)d_in[4];
    const float* w2  = (const float*)d_in[5];
    const float* b2  = (const float*)d_in[6];
    float* out = (float*)d_out;

    char* ws = (char*)d_ws;
    __hip_bfloat16* bufA = (__hip_bfloat16*)ws;                 // 66,064,384 B
    __hip_bfloat16* w1t  = (__hip_bfloat16*)(ws + 66064384);    // 4,096 B
    __hip_bfloat16* w2h  = (__hip_bfloat16*)(ws + 66068480);    // 147,456 B
    __half* xf = (__half*)(ws + 66215936);                      // 31,490,048
    __half* k1 = (__half*)(ws + 97705984);                      // 1,605,632
    __half* k2 = (__half*)(ws + 99311616);                      // end 100,917,248

    wt_xform_all<<<296, 256, 0, stream>>>(w1, w2, w1t, w2h);

    conv1_mfma<<<dim3(256, 1, 32), 256, 0, stream>>>(img, w1t, b1, bufA,
                                                     256, 256, 127, 127, 16);
    conv2_mfma<<<dim3(128, 1, 32), 256, 0, stream>>>(bufA, w2h, b2, xf,
                                                     127, 127, 62, 62, 16);

    conv1_mfma<<<dim3(16, 1, 32), 256, 0, stream>>>(t1, w1t, b1, bufA,
                                                    64, 64, 31, 31, 4);
    conv2_mfma<<<dim3(8, 1, 32), 256, 0, stream>>>(bufA, w2h, b2, k1,
                                                   31, 31, 14, 14, 4);
    conv1_mfma<<<dim3(16, 1, 32), 256, 0, stream>>>(t2, w1t, b1, bufA,
                                                    64, 64, 31, 31, 4);
    conv2_mfma<<<dim3(8, 1, 32), 256, 0, stream>>>(bufA, w2h, b2, k2,
                                                   31, 31, 14, 14, 4);

    xcorr_dual<<<4096, 384, 0, stream>>>(xf, k1, k2, out, out + (size_t)9834496);
}